// Round 4
// baseline (3585.248 us; speedup 1.0000x reference)
//
#include <hip/hip_runtime.h>
#include <math.h>

#define ROI 400
#define HEADS 4
#define DH 100
#define NB 64
#define HIDF 800
#define NC 2
#define KPOOL 280
#define ATT_SCALE 0.1f

// ---------------------------------------------------------------- preprocess
__global__ __launch_bounds__(256) void pre_reduce_kernel(const float* __restrict__ in,
                                                         float* __restrict__ meanb,
                                                         float* __restrict__ stdb) {
  int b = blockIdx.x;
  const float* p = in + (size_t)b * ROI * (2 * ROI);
  double s = 0.0, ss = 0.0;
  const int n = ROI * ROI;
  for (int e = threadIdx.x; e < n; e += blockDim.x) {
    int r = e / ROI, c = e % ROI;
    float v = log10f(p[(size_t)r * (2 * ROI) + ROI + c] + 1.0f);
    s += v; ss += (double)v * (double)v;
  }
  __shared__ double rs[256], rss[256];
  rs[threadIdx.x] = s; rss[threadIdx.x] = ss;
  __syncthreads();
  for (int st = 128; st > 0; st >>= 1) {
    if (threadIdx.x < st) { rs[threadIdx.x] += rs[threadIdx.x + st]; rss[threadIdx.x] += rss[threadIdx.x + st]; }
    __syncthreads();
  }
  if (threadIdx.x == 0) {
    double mean = rs[0] / n;
    double var = (rss[0] - rs[0] * rs[0] / n) / (double)(n - 1);
    meanb[b] = (float)mean;
    stdb[b]  = (float)(sqrt(var) + 1e-6);
  }
}

__global__ __launch_bounds__(256) void build_xm_kernel(const float* __restrict__ in,
                                                       const float* __restrict__ sel,
                                                       const float* __restrict__ meanb,
                                                       const float* __restrict__ stdb,
                                                       float* __restrict__ X, float* __restrict__ M) {
  size_t e = (size_t)blockIdx.x * blockDim.x + threadIdx.x;
  const size_t total = (size_t)NB * ROI * ROI;
  if (e >= total) return;
  int c = (int)(e % ROI);
  int r = (int)((e / ROI) % ROI);
  int b = (int)(e / ((size_t)ROI * ROI));
  const float* row = in + ((size_t)b * ROI + r) * (2 * ROI);
  X[e] = row[c];
  float v = log10f(row[ROI + c] + 1.0f);
  float sg = 1.0f / (1.0f + expf(-sel[r * ROI + c]));
  M[e] = ((v - meanb[b]) / stdb[b]) * sg;
}

// ---------------------------------------------------------------- QKV weight pack
__global__ __launch_bounds__(256) void pack_qkv_kernel(const float* __restrict__ wq, const float* __restrict__ wk,
                                                       const float* __restrict__ wv, float* __restrict__ wp) {
  int e = blockIdx.x * 256 + threadIdx.x;
  if (e >= ROI * 3 * ROI) return;
  int k = e / (3 * ROI), c = e % (3 * ROI);
  float v;
  if (c < ROI) v = wq[k * ROI + c];
  else if (c < 2 * ROI) v = wk[k * ROI + c - ROI];
  else v = wv[k * ROI + c - 2 * ROI];
  wp[e] = v;
}

// ---------------------------------------------------------------- GEMM  128x64 tile, 8x8 micro, 128 thr
// C[M,N] = A[M,K] @ W[K,N]  (+bias, +res, +gelu per EPI). M%128==0, K%16==0, N guarded.
#define GBM 128
#define GBN 64
#define GBK 16
#define APAD 132

template<int EPI>
__global__ __launch_bounds__(128) void gemm_kernel(const float* __restrict__ A, const float* __restrict__ W,
                                                   const float* __restrict__ bias, const float* __restrict__ res,
                                                   float* __restrict__ C, int M, int N, int K) {
  __shared__ __align__(16) float As[GBK][APAD];   // transposed A tile [k][row]
  __shared__ __align__(16) float Bs[GBK][GBN];
  const int tid = threadIdx.x;
  const int bm = blockIdx.y * GBM;
  const int bn = blockIdx.x * GBN;
  const int trg = tid >> 3;        // 0..15 -> rows trg*8 .. +7
  const int tcg = tid & 7;         // 0..7  -> cols tcg*8 .. +7
  float acc[8][8] = {};

  const int sar = tid >> 2;        // A-stage row within 32-group
  const int sak = (tid & 3) << 2;  // A-stage k offset
  const int sbk = tid >> 4;        // B-stage k row (0..7, +8 per it)
  const int sbc = (tid & 15) << 2; // B-stage col offset

  for (int k0 = 0; k0 < K; k0 += GBK) {
#pragma unroll
    for (int it = 0; it < 4; ++it) {
      int r = it * 32 + sar;
      float4 av = *(const float4*)(A + (size_t)(bm + r) * K + k0 + sak);
      As[sak + 0][r] = av.x; As[sak + 1][r] = av.y;
      As[sak + 2][r] = av.z; As[sak + 3][r] = av.w;
    }
#pragma unroll
    for (int it = 0; it < 2; ++it) {
      int row = sbk + 8 * it;
      const float* wrow = W + (size_t)(k0 + row) * N;
      int wc = bn + sbc;
      float4 wv;
      if (wc + 3 < N) {
        wv = *(const float4*)(wrow + wc);
      } else {
        wv.x = (wc + 0 < N) ? wrow[wc + 0] : 0.f;
        wv.y = (wc + 1 < N) ? wrow[wc + 1] : 0.f;
        wv.z = (wc + 2 < N) ? wrow[wc + 2] : 0.f;
        wv.w = (wc + 3 < N) ? wrow[wc + 3] : 0.f;
      }
      *(float4*)&Bs[row][sbc] = wv;
    }
    __syncthreads();
#pragma unroll
    for (int kk = 0; kk < GBK; ++kk) {
      float4 a0 = *(const float4*)&As[kk][trg * 8 + 0];
      float4 a1 = *(const float4*)&As[kk][trg * 8 + 4];
      float4 b0 = *(const float4*)&Bs[kk][tcg * 8 + 0];
      float4 b1 = *(const float4*)&Bs[kk][tcg * 8 + 4];
      const float af[8] = {a0.x, a0.y, a0.z, a0.w, a1.x, a1.y, a1.z, a1.w};
      const float bf[8] = {b0.x, b0.y, b0.z, b0.w, b1.x, b1.y, b1.z, b1.w};
#pragma unroll
      for (int i = 0; i < 8; ++i) {
#pragma unroll
        for (int j = 0; j < 8; ++j) acc[i][j] += af[i] * bf[j];
      }
    }
    __syncthreads();
  }

  // epilogue
  const int col = bn + tcg * 8;
  float bv[8];
#pragma unroll
  for (int j = 0; j < 8; ++j) bv[j] = 0.f;
  if (EPI >= 1) {
#pragma unroll
    for (int j = 0; j < 8; ++j) bv[j] = (col + j < N) ? bias[col + j] : 0.f;
  }
#pragma unroll
  for (int i = 0; i < 8; ++i) {
    int row = bm + trg * 8 + i;
    if (col + 7 < N) {
      float v[8];
#pragma unroll
      for (int j = 0; j < 8; ++j) v[j] = acc[i][j] + bv[j];
      if (EPI == 2) {
        float4 r0 = *(const float4*)(res + (size_t)row * N + col);
        float4 r1 = *(const float4*)(res + (size_t)row * N + col + 4);
        v[0] += r0.x; v[1] += r0.y; v[2] += r0.z; v[3] += r0.w;
        v[4] += r1.x; v[5] += r1.y; v[6] += r1.z; v[7] += r1.w;
      }
      if (EPI == 3) {
#pragma unroll
        for (int j = 0; j < 8; ++j) v[j] = 0.5f * v[j] * (1.0f + erff(v[j] * 0.70710678118654752f));
      }
      *(float4*)(C + (size_t)row * N + col) = make_float4(v[0], v[1], v[2], v[3]);
      *(float4*)(C + (size_t)row * N + col + 4) = make_float4(v[4], v[5], v[6], v[7]);
    } else {
#pragma unroll
      for (int j = 0; j < 8; ++j) {
        if (col + j < N) {
          float v = acc[i][j] + bv[j];
          if (EPI == 2) v += res[(size_t)row * N + col + j];
          if (EPI == 3) v = 0.5f * v * (1.0f + erff(v * 0.70710678118654752f));
          C[(size_t)row * N + col + j] = v;
        }
      }
    }
  }
}

// ---------------------------------------------------------------- fused flash attention
// block = 256 threads, 64 query rows of one (b, h). Tiles over 32 keys. ldq = QKV row stride.
// LDS: 25.6 + 13.3 + 9.2 = 48.1 KB -> 3 blocks/CU.
#define BI 64
#define BJ 32

__global__ __launch_bounds__(256) void fattn_kernel(const float* __restrict__ Q, const float* __restrict__ K,
                                                    const float* __restrict__ V, const float* __restrict__ Mm,
                                                    float* __restrict__ O, int N, int ldq) {
  __shared__ __align__(16) float Qst[DH][BI];     // 25.6 KB
  __shared__ __align__(16) float KV[BJ * 104];    // union Kst[DH][BJ] / Vs[BJ][104]  13.3 KB
  __shared__ __align__(16) float Ss[BI][36];      // 9.2 KB
  float (*Kst)[BJ]  = (float (*)[BJ])KV;
  float (*Vs)[104]  = (float (*)[104])KV;

  const int tid = threadIdx.x;
  const int tr = tid >> 4;   // 0..15 -> rows 4tr..4tr+3
  const int tc = tid & 15;   // 0..15 -> cols 2tc, 2tc+1
  const int i0 = blockIdx.x * BI;
  const int h  = blockIdx.y;
  const int b  = blockIdx.z;

  const float* Qb = Q + (size_t)b * N * ldq + h * DH;
  const float* Kb = K + (size_t)b * N * ldq + h * DH;
  const float* Vb = V + (size_t)b * N * ldq + h * DH;

  for (int e = tid; e < (DH / 4) * BI; e += 256) {
    int c = e >> 6, r = e & 63;
    int gi = i0 + r; if (gi >= N) gi = N - 1;
    float4 v = *(const float4*)(Qb + (size_t)gi * ldq + 4 * c);
    Qst[4 * c + 0][r] = v.x; Qst[4 * c + 1][r] = v.y;
    Qst[4 * c + 2][r] = v.z; Qst[4 * c + 3][r] = v.w;
  }

  float m_i[4], l_i[4];
  float oa[4][4] = {};
  float ob[4][4] = {};
#pragma unroll
  for (int i = 0; i < 4; ++i) { m_i[i] = -INFINITY; l_i[i] = 0.f; }

  const int njt = (N + BJ - 1) / BJ;
  for (int jt = 0; jt < njt; ++jt) {
    const int j0 = jt * BJ;
    __syncthreads();   // prev PV done with Vs (union with Kst)
    for (int e = tid; e < (DH / 4) * BJ; e += 256) {
      int c = e >> 5, r = e & 31;
      int gj = j0 + r; if (gj >= N) gj = N - 1;
      float4 v = *(const float4*)(Kb + (size_t)gj * ldq + 4 * c);
      Kst[4 * c + 0][r] = v.x; Kst[4 * c + 1][r] = v.y;
      Kst[4 * c + 2][r] = v.z; Kst[4 * c + 3][r] = v.w;
    }
    __syncthreads();

    // S tile: 64x32x100, 4x2 per thread
    float sacc[4][2] = {};
#pragma unroll 4
    for (int kk = 0; kk < DH; ++kk) {
      float4 a   = *(const float4*)&Qst[kk][4 * tr];
      float2 kb2 = *(const float2*)&Kst[kk][2 * tc];
      sacc[0][0] += a.x * kb2.x; sacc[0][1] += a.x * kb2.y;
      sacc[1][0] += a.y * kb2.x; sacc[1][1] += a.y * kb2.y;
      sacc[2][0] += a.z * kb2.x; sacc[2][1] += a.z * kb2.y;
      sacc[3][0] += a.w * kb2.x; sacc[3][1] += a.w * kb2.y;
    }

    // online softmax over 16-lane row groups (each lane holds 2 cols)
    const float* Mbase = Mm + (size_t)b * N * N;
    const int c0 = j0 + 2 * tc;
#pragma unroll
    for (int i = 0; i < 4; ++i) {
      int gi = i0 + 4 * tr + i; if (gi >= N) gi = N - 1;
      const float* Mr = Mbase + (size_t)gi * N + c0;
      float mv0 = 0.f, mv1 = 0.f;
      if (c0 + 1 < N) { float2 m2 = *(const float2*)Mr; mv0 = m2.x; mv1 = m2.y; }
      else if (c0 < N) { mv0 = Mr[0]; }
      float s0 = (c0 < N)     ? sacc[i][0] * ATT_SCALE * (1.0f + mv0) : -INFINITY;
      float s1 = (c0 + 1 < N) ? sacc[i][1] * ATT_SCALE * (1.0f + mv1) : -INFINITY;
      float rm = fmaxf(s0, s1);
      rm = fmaxf(rm, __shfl_xor(rm, 1, 16));
      rm = fmaxf(rm, __shfl_xor(rm, 2, 16));
      rm = fmaxf(rm, __shfl_xor(rm, 4, 16));
      rm = fmaxf(rm, __shfl_xor(rm, 8, 16));
      float nm = fmaxf(m_i[i], rm);
      float f = expf(m_i[i] - nm);
      float p0 = expf(s0 - nm);
      float p1 = expf(s1 - nm);
      float ts = p0 + p1;
      ts += __shfl_xor(ts, 1, 16);
      ts += __shfl_xor(ts, 2, 16);
      ts += __shfl_xor(ts, 4, 16);
      ts += __shfl_xor(ts, 8, 16);
      l_i[i] = l_i[i] * f + ts;
      m_i[i] = nm;
#pragma unroll
      for (int q = 0; q < 4; ++q) { oa[i][q] *= f; ob[i][q] *= f; }
      *(float2*)&Ss[4 * tr + i][2 * tc] = make_float2(p0, p1);
    }
    __syncthreads();   // Ss ready; Kst reads done -> reuse as Vs

    for (int e = tid; e < (DH / 4) * BJ; e += 256) {
      int c = e % 25, r = e / 25;
      int gj = j0 + r; if (gj >= N) gj = N - 1;
      *(float4*)&Vs[r][4 * c] = *(const float4*)(Vb + (size_t)gj * ldq + 4 * c);
    }
    __syncthreads();

#pragma unroll 2
    for (int jj = 0; jj < BJ / 4; ++jj) {
      float4 p0 = *(const float4*)&Ss[4 * tr + 0][4 * jj];
      float4 p1 = *(const float4*)&Ss[4 * tr + 1][4 * jj];
      float4 p2 = *(const float4*)&Ss[4 * tr + 2][4 * jj];
      float4 p3 = *(const float4*)&Ss[4 * tr + 3][4 * jj];
      float pv[4][4] = {{p0.x, p0.y, p0.z, p0.w}, {p1.x, p1.y, p1.z, p1.w},
                        {p2.x, p2.y, p2.z, p2.w}, {p3.x, p3.y, p3.z, p3.w}};
#pragma unroll
      for (int q = 0; q < 4; ++q) {
        int j = 4 * jj + q;
        float4 va = *(const float4*)&Vs[j][4 * tc];
        float4 vb = *(const float4*)&Vs[j][64 + 4 * tc];
#pragma unroll
        for (int i = 0; i < 4; ++i) {
          oa[i][0] += pv[i][q] * va.x; oa[i][1] += pv[i][q] * va.y;
          oa[i][2] += pv[i][q] * va.z; oa[i][3] += pv[i][q] * va.w;
          ob[i][0] += pv[i][q] * vb.x; ob[i][1] += pv[i][q] * vb.y;
          ob[i][2] += pv[i][q] * vb.z; ob[i][3] += pv[i][q] * vb.w;
        }
      }
    }
  }

  const int HD = HEADS * DH;
  float* Ob = O + (size_t)b * N * HD + h * DH;
#pragma unroll
  for (int i = 0; i < 4; ++i) {
    int gi = i0 + 4 * tr + i;
    if (gi < N) {
      float inv = 1.0f / l_i[i];
      float4 w = make_float4(oa[i][0] * inv, oa[i][1] * inv, oa[i][2] * inv, oa[i][3] * inv);
      *(float4*)(Ob + (size_t)gi * HD + 4 * tc) = w;
      if (tc < 9) {
        float4 w2 = make_float4(ob[i][0] * inv, ob[i][1] * inv, ob[i][2] * inv, ob[i][3] * inv);
        *(float4*)(Ob + (size_t)gi * HD + 64 + 4 * tc) = w2;
      }
    }
  }
}

// ---------------------------------------------------------------- layernorm
__global__ __launch_bounds__(128) void ln_kernel(const float* __restrict__ Y, const float* __restrict__ g,
                                                 const float* __restrict__ bta, float* __restrict__ X) {
  int row = blockIdx.x;
  const float* y = Y + (size_t)row * ROI;
  float* x = X + (size_t)row * ROI;
  int tid = threadIdx.x;
  __shared__ float red[128];
  float s = 0.f;
  for (int c = tid; c < ROI; c += 128) s += y[c];
  red[tid] = s; __syncthreads();
  for (int st = 64; st > 0; st >>= 1) { if (tid < st) red[tid] += red[tid + st]; __syncthreads(); }
  float mu = red[0] / ROI;
  __syncthreads();
  float v = 0.f;
  for (int c = tid; c < ROI; c += 128) { float d = y[c] - mu; v += d * d; }
  red[tid] = v; __syncthreads();
  for (int st = 64; st > 0; st >>= 1) { if (tid < st) red[tid] += red[tid + st]; __syncthreads(); }
  float rstd = rsqrtf(red[0] / ROI + 1e-5f);
  for (int c = tid; c < ROI; c += 128) x[c] = (y[c] - mu) * rstd * g[c] + bta[c];
}

// ---------------------------------------------------------------- classifier head
__global__ __launch_bounds__(128) void cls_kernel(const float* __restrict__ X, const float* __restrict__ r1w,
                                                  const float* __restrict__ r1b, const float* __restrict__ r2w,
                                                  const float* __restrict__ r2b, float* __restrict__ probs, int N) {
  int b = blockIdx.x, tid = threadIdx.x;
  __shared__ float gf[ROI];
  __shared__ float hid[128];
  for (int c = tid; c < ROI; c += 128) {
    float s = 0.f;
    for (int n = 0; n < N; ++n) s += X[((size_t)b * N + n) * ROI + c];
    gf[c] = s / (float)N;
  }
  __syncthreads();
  {
    float a = r1b[tid];
    for (int k = 0; k < ROI; ++k) a += gf[k] * r1w[k * 128 + tid];
    hid[tid] = (a >= 0.f) ? a : 0.01f * a;
  }
  __syncthreads();
  if (tid < NC) {
    float l = r2b[tid];
    for (int k = 0; k < 128; ++k) l += hid[k] * r2w[k * NC + tid];
    gf[tid] = l;
  }
  __syncthreads();
  if (tid == 0) {
    float m = fmaxf(gf[0], gf[1]);
    float e0 = expf(gf[0] - m), e1 = expf(gf[1] - m);
    float inv = 1.f / (e0 + e1);
    probs[b * NC + 0] = e0 * inv;
    probs[b * NC + 1] = e1 * inv;
  }
}

// ---------------------------------------------------------------- pooling
__global__ __launch_bounds__(128) void score_kernel(const float* __restrict__ M, const float* __restrict__ X,
                                                    const float* __restrict__ pws, const float* __restrict__ pwf,
                                                    const float* __restrict__ pmw, const float* __restrict__ pmb,
                                                    float* __restrict__ scores) {
  int i = blockIdx.x, b = blockIdx.y, tid = threadIdx.x;
  const float* mr = M + ((size_t)b * ROI + i) * ROI;
  const float* xr = X + ((size_t)b * ROI + i) * ROI;
  float s1 = 0.f, s2 = 0.f;
  for (int j = tid; j < ROI; j += 128) { s1 += mr[j] * pws[j]; s2 += xr[j] * pwf[j]; }
  __shared__ float r1[128], r2[128];
  r1[tid] = s1; r2[tid] = s2; __syncthreads();
  for (int st = 64; st > 0; st >>= 1) {
    if (tid < st) { r1[tid] += r1[tid + st]; r2[tid] += r2[tid + st]; }
    __syncthreads();
  }
  if (tid == 0) {
    float a = fabsf(r1[0]), c = fabsf(r2[0]);
    float z = a * pmw[0] + c * pmw[1] + pmb[0];
    scores[b * ROI + i] = 1.f / (1.f + expf(-z));
  }
}

__global__ __launch_bounds__(128) void select_kernel(const float* __restrict__ scores, int* __restrict__ idx) {
  int b = blockIdx.x, tid = threadIdx.x;
  __shared__ float sc[ROI];
  __shared__ int sel[ROI];
  for (int i = tid; i < ROI; i += 128) sc[i] = scores[b * ROI + i];
  __syncthreads();
  for (int i = tid; i < ROI; i += 128) {
    float si = sc[i];
    int rank = 0;
    for (int j = 0; j < ROI; ++j) {
      float sj = sc[j];
      rank += (sj > si) || (sj == si && j < i);
    }
    sel[i] = (rank < KPOOL) ? 1 : 0;
  }
  __syncthreads();
  for (int i = tid; i < ROI; i += 128) {
    if (sel[i]) {
      int pos = 0;
      for (int j = 0; j < i; ++j) pos += sel[j];
      idx[b * KPOOL + pos] = i;
    }
  }
}

__global__ __launch_bounds__(128) void gatherx_kernel(const float* __restrict__ X, const float* __restrict__ scores,
                                                      const int* __restrict__ idx, float* __restrict__ Xp) {
  int p = blockIdx.x % KPOOL, b = blockIdx.x / KPOOL, tid = threadIdx.x;
  int src = idx[b * KPOOL + p];
  float sw = scores[b * ROI + src];
  const float* xr = X + ((size_t)b * ROI + src) * ROI;
  float* o = Xp + ((size_t)b * KPOOL + p) * ROI;
  for (int c = tid; c < ROI; c += 128) o[c] = xr[c] * sw;
}

__global__ __launch_bounds__(128) void gatherm_kernel(const float* __restrict__ M, const int* __restrict__ idx,
                                                      float* __restrict__ Mp) {
  int p = blockIdx.x % KPOOL, b = blockIdx.x / KPOOL, tid = threadIdx.x;
  __shared__ int id[KPOOL];
  for (int q = tid; q < KPOOL; q += 128) id[q] = idx[b * KPOOL + q];
  __syncthreads();
  int src = idx[b * KPOOL + p];
  const float* mr = M + ((size_t)b * ROI + src) * ROI;
  float* o = Mp + ((size_t)b * KPOOL + p) * KPOOL;
  for (int q = tid; q < KPOOL; q += 128) o[q] = mr[id[q]];
}

// ---------------------------------------------------------------- final output
__global__ __launch_bounds__(128) void final_kernel(const float* __restrict__ X, const float* __restrict__ probs,
                                                    float* __restrict__ out, int N) {
  int b = blockIdx.x, tid = threadIdx.x;
  __shared__ float f[ROI];
  __shared__ float red[128];
  for (int c = tid; c < ROI; c += 128) {
    float s = 0.f;
    for (int n = 0; n < N; ++n) s += X[((size_t)b * N + n) * ROI + c];
    f[c] = s / (float)N;
  }
  __syncthreads();
  float ls = 0.f;
  for (int c = tid; c < ROI; c += 128) ls += f[c] * f[c];
  red[tid] = ls; __syncthreads();
  for (int st = 64; st > 0; st >>= 1) { if (tid < st) red[tid] += red[tid + st]; __syncthreads(); }
  float inv = 1.f / fmaxf(sqrtf(red[0]), 1e-12f);
  for (int c = tid; c < ROI; c += 128) out[b * ROI + c] = f[c] * inv;
  if (tid < NC) out[NB * ROI + b * NC + tid] = 0.5f * (probs[b * NC + tid] + probs[NB * NC + b * NC + tid]);
}

// ---------------------------------------------------------------- host orchestration
static inline void gemm_launch0(const float* A, const float* W, float* C, int M, int N, int K, hipStream_t st) {
  dim3 g((N + GBN - 1) / GBN, M / GBM);
  gemm_kernel<0><<<g, 128, 0, st>>>(A, W, nullptr, nullptr, C, M, N, K);
}
static inline void gemm_launch2(const float* A, const float* W, const float* bias, const float* res, float* C,
                                int M, int N, int K, hipStream_t st) {
  dim3 g((N + GBN - 1) / GBN, M / GBM);
  gemm_kernel<2><<<g, 128, 0, st>>>(A, W, bias, res, C, M, N, K);
}
static inline void gemm_launch3(const float* A, const float* W, const float* bias, float* C,
                                int M, int N, int K, hipStream_t st) {
  dim3 g((N + GBN - 1) / GBN, M / GBM);
  gemm_kernel<3><<<g, 128, 0, st>>>(A, W, bias, nullptr, C, M, N, K);
}

extern "C" void kernel_launch(void* const* d_in, const int* in_sizes, int n_in,
                              void* d_out, int out_size, void* d_ws, size_t ws_size,
                              hipStream_t stream) {
  const float* in  = (const float*)d_in[0];
  const float* sel = (const float*)d_in[1];
  const float* wq  = (const float*)d_in[2];
  const float* wk  = (const float*)d_in[3];
  const float* wv  = (const float*)d_in[4];
  const float* wo  = (const float*)d_in[5];
  const float* bo  = (const float*)d_in[6];
  const float* w1  = (const float*)d_in[7];
  const float* b1  = (const float*)d_in[8];
  const float* w2  = (const float*)d_in[9];
  const float* b2  = (const float*)d_in[10];
  const float* lng = (const float*)d_in[11];
  const float* lnb = (const float*)d_in[12];
  const float* pws = (const float*)d_in[13];
  const float* pwf = (const float*)d_in[14];
  const float* pmw = (const float*)d_in[15];
  const float* pmb = (const float*)d_in[16];
  const float* r1w = (const float*)d_in[17];
  const float* r1b = (const float*)d_in[18];
  const float* r2w = (const float*)d_in[19];
  const float* r2b = (const float*)d_in[20];
  float* out = (float*)d_out;

  float* ws = (float*)d_ws;
  const size_t AT = (size_t)NB * ROI * ROI;  // 10,240,000 floats per slab
  float* A0 = ws;
  float* A1 = ws + AT;
  float* A2 = ws + 2 * AT;
  float* A3 = ws + 3 * AT;
  float* A4 = ws + 4 * AT;
  float* A5 = ws + 5 * AT;
  float* smalls = ws + 6 * AT;
  float* meanb = smalls;                 // 64
  float* stdb  = smalls + 64;            // 64
  float* scores = smalls + 128;          // 64*400
  int*   idx = (int*)(smalls + 128 + NB * ROI);        // 64*280 ints
  float* probs = smalls + 128 + NB * ROI + NB * KPOOL; // 2*64*2

  const int NQKV = 3 * ROI;  // 1200
  const int packGrid = (ROI * NQKV + 255) / 256;

  pre_reduce_kernel<<<NB, 256, 0, stream>>>(in, meanb, stdb);
  build_xm_kernel<<<(int)((AT + 255) / 256), 256, 0, stream>>>(in, sel, meanb, stdb, A0, A1);

  // ---------------- depth 0: N=400, x=A0, m=A1
  {
    const int N = ROI;
    const int Mtok = NB * N;  // 25600
    const float* x = A0;
    const float* m = A1;
    float* wp = A5;            // packed QKV weights (dead once QKV gemm completes)
    pack_qkv_kernel<<<packGrid, 256, 0, stream>>>(wq, wk, wv, wp);
    float* QKV = A2;           // spans A2..A4: Mtok x 1200
    gemm_launch0(x, wp, QKV, Mtok, NQKV, ROI, stream);
    float* O = A5;             // over wp (dead)
    fattn_kernel<<<dim3((N + BI - 1) / BI, HEADS, NB), 256, 0, stream>>>(
        QKV, QKV + ROI, QKV + 2 * ROI, m, O, N, NQKV);
    float* Xa = A2;            // over QKV
    gemm_launch2(O, wo + 0, bo + 0, x, Xa, Mtok, ROI, ROI, stream);
    float* H = A3;             // spans A3..A4
    gemm_launch3(Xa, w1 + 0, b1 + 0, H, Mtok, HIDF, ROI, stream);
    float* Y = A5;             // over O
    gemm_launch2(H, w2 + 0, b2 + 0, Xa, Y, Mtok, ROI, HIDF, stream);
    float* Xn = A0;            // over x
    ln_kernel<<<Mtok, 128, 0, stream>>>(Y, lng + 0, lnb + 0, Xn);
    cls_kernel<<<NB, 128, 0, stream>>>(Xn, r1w + 0, r1b + 0, r2w + 0, r2b + 0, probs, N);
    score_kernel<<<dim3(ROI, NB), 128, 0, stream>>>(m, Xn, pws, pwf, pmw, pmb, scores);
    select_kernel<<<NB, 128, 0, stream>>>(scores, idx);
    gatherx_kernel<<<NB * KPOOL, 128, 0, stream>>>(Xn, scores, idx, A3);  // Xp -> A3
    gatherm_kernel<<<NB * KPOOL, 128, 0, stream>>>(m, idx, A4);            // Mp -> A4
  }

  // ---------------- depth 1: N=280, x=A3, m=A4
  {
    const int N = KPOOL;
    const int Mtok = NB * N;  // 17920
    const float* x = A3;
    const float* m = A4;
    const int d = 1;
    const float* wq1 = wq + (size_t)d * ROI * ROI;
    const float* wk1 = wk + (size_t)d * ROI * ROI;
    const float* wv1 = wv + (size_t)d * ROI * ROI;
    const float* wo1 = wo + (size_t)d * ROI * ROI;
    const float* bo1 = bo + (size_t)d * ROI;
    const float* w11 = w1 + (size_t)d * ROI * HIDF;
    const float* b11 = b1 + (size_t)d * HIDF;
    const float* w21 = w2 + (size_t)d * HIDF * ROI;
    const float* b21 = b2 + (size_t)d * ROI;
    const float* lng1 = lng + (size_t)d * ROI;
    const float* lnb1 = lnb + (size_t)d * ROI;
    const float* r1w1 = r1w + (size_t)d * ROI * 128;
    const float* r1b1 = r1b + (size_t)d * 128;
    const float* r2w1 = r2w + (size_t)d * 128 * NC;
    const float* r2b1 = r2b + (size_t)d * NC;

    float* wp = A5;            // packed QKV weights depth 1
    pack_qkv_kernel<<<packGrid, 256, 0, stream>>>(wq1, wk1, wv1, wp);
    float* QKV = A0;           // spans A0..A2: 17920 x 1200 (2.1 slabs)
    gemm_launch0(x, wp, QKV, Mtok, NQKV, ROI, stream);
    float* O = A5;             // over wp
    fattn_kernel<<<dim3((N + BI - 1) / BI, HEADS, NB), 256, 0, stream>>>(
        QKV, QKV + ROI, QKV + 2 * ROI, m, O, N, NQKV);
    float* Xa = A0;            // over QKV
    gemm_launch2(O, wo1, bo1, x, Xa, Mtok, ROI, ROI, stream);
    float* H = A1;             // spans A1..A2
    gemm_launch3(Xa, w11, b11, H, Mtok, HIDF, ROI, stream);
    float* Y = A5;             // over O
    gemm_launch2(H, w21, b21, Xa, Y, Mtok, ROI, HIDF, stream);
    float* Xf = A1;            // over H
    ln_kernel<<<Mtok, 128, 0, stream>>>(Y, lng1, lnb1, Xf);
    cls_kernel<<<NB, 128, 0, stream>>>(Xf, r1w1, r1b1, r2w1, r2b1, probs + NB * NC, N);
    final_kernel<<<NB, 128, 0, stream>>>(Xf, probs, out, N);
  }
  (void)in_sizes; (void)n_in; (void)out_size; (void)ws_size;
}

// Round 5
// 2763.114 us; speedup vs baseline: 1.2975x; 1.2975x over previous
//
#include <hip/hip_runtime.h>
#include <math.h>

#define ROI 400
#define HEADS 4
#define DH 100
#define NB 64
#define HIDF 800
#define NC 2
#define KPOOL 280
#define ATT_SCALE 0.1f

typedef __attribute__((ext_vector_type(8))) short short8v;
typedef __attribute__((ext_vector_type(8))) unsigned short u16x8;
typedef __attribute__((ext_vector_type(4))) float f32x4;

__device__ __forceinline__ unsigned short f2bf(float x) {
  unsigned int u = __float_as_uint(x);
  u += 0x7fffu + ((u >> 16) & 1u);
  return (unsigned short)(u >> 16);
}
__device__ __forceinline__ void split2(float x, unsigned short& h, unsigned short& l) {
  h = f2bf(x);
  float hf = __uint_as_float(((unsigned int)h) << 16);
  l = f2bf(x - hf);
}

// ---------------------------------------------------------------- preprocess
__global__ __launch_bounds__(256) void pre_reduce_kernel(const float* __restrict__ in,
                                                         float* __restrict__ meanb,
                                                         float* __restrict__ stdb) {
  int b = blockIdx.x;
  const float* p = in + (size_t)b * ROI * (2 * ROI);
  double s = 0.0, ss = 0.0;
  const int n = ROI * ROI;
  for (int e = threadIdx.x; e < n; e += blockDim.x) {
    int r = e / ROI, c = e % ROI;
    float v = log10f(p[(size_t)r * (2 * ROI) + ROI + c] + 1.0f);
    s += v; ss += (double)v * (double)v;
  }
  __shared__ double rs[256], rss[256];
  rs[threadIdx.x] = s; rss[threadIdx.x] = ss;
  __syncthreads();
  for (int st = 128; st > 0; st >>= 1) {
    if (threadIdx.x < st) { rs[threadIdx.x] += rs[threadIdx.x + st]; rss[threadIdx.x] += rss[threadIdx.x + st]; }
    __syncthreads();
  }
  if (threadIdx.x == 0) {
    double mean = rs[0] / n;
    double var = (rss[0] - rs[0] * rs[0] / n) / (double)(n - 1);
    meanb[b] = (float)mean;
    stdb[b]  = (float)(sqrt(var) + 1e-6);
  }
}

__global__ __launch_bounds__(256) void build_m_kernel(const float* __restrict__ in,
                                                      const float* __restrict__ sel,
                                                      const float* __restrict__ meanb,
                                                      const float* __restrict__ stdb,
                                                      float* __restrict__ M) {
  size_t e = (size_t)blockIdx.x * blockDim.x + threadIdx.x;
  const size_t total = (size_t)NB * ROI * ROI;
  if (e >= total) return;
  int c = (int)(e % ROI);
  int r = (int)((e / ROI) % ROI);
  int b = (int)(e / ((size_t)ROI * ROI));
  const float* row = in + ((size_t)b * ROI + r) * (2 * ROI);
  float v = log10f(row[ROI + c] + 1.0f);
  float sg = 1.0f / (1.0f + expf(-sel[r * ROI + c]));
  M[e] = ((v - meanb[b]) / stdb[b]) * sg;
}

// ---------------------------------------------------------------- weight pack: W[K][N] -> WT hi/lo [N][K]
__global__ __launch_bounds__(256) void packw_kernel(const float* __restrict__ W, int K, int N,
                                                    unsigned short* __restrict__ WH,
                                                    unsigned short* __restrict__ WL) {
  __shared__ float t[64][68];
  int bk = blockIdx.y * 64, bn = blockIdx.x * 64;
  int r = threadIdx.x >> 2;
  int c0 = (threadIdx.x & 3) << 4;
  int gk = bk + r;
#pragma unroll
  for (int i = 0; i < 4; ++i) {
    int c = c0 + 4 * i;
    float4 v = make_float4(0.f, 0.f, 0.f, 0.f);
    if (gk < K && bn + c < N) v = *(const float4*)(W + (size_t)gk * N + bn + c);
    *(float4*)&t[r][c] = v;
  }
  __syncthreads();
  int gn = bn + r;
#pragma unroll
  for (int i = 0; i < 4; ++i) {
    int c = c0 + 4 * i;      // k-local
    int gkk = bk + c;
    if (gn < N && gkk < K) {
      ushort4 h, l;
      split2(t[c + 0][r], h.x, l.x);
      split2(t[c + 1][r], h.y, l.y);
      split2(t[c + 2][r], h.z, l.z);
      split2(t[c + 3][r], h.w, l.w);
      *(ushort4*)(WH + (size_t)gn * K + gkk) = h;
      *(ushort4*)(WL + (size_t)gn * K + gkk) = l;
    }
  }
}

// ---------------------------------------------------------------- MFMA split-bf16 GEMM
// C[M][N] = A[M][K](fp32, lda) @ W[K][N] (packed WT hi/lo [N][K])
// EPI: 0 none, 2 +bias+res(ldr), 3 +bias+gelu.  M%128==0, K%4==0, N guarded.
#define TBM 128
#define TBN 128
#define TBK 32
#define KP 40

template<int EPI>
__global__ __launch_bounds__(256) void mgemm_kernel(const float* __restrict__ A, int lda,
                                                    const unsigned short* __restrict__ WH,
                                                    const unsigned short* __restrict__ WL,
                                                    const float* __restrict__ bias,
                                                    const float* __restrict__ res, int ldr,
                                                    float* __restrict__ C, int M, int N, int K) {
  __shared__ unsigned short Ah[TBM][KP], Al[TBM][KP], Bh[TBN][KP], Bl[TBN][KP];
  const int tid = threadIdx.x;
  const int lane = tid & 63;
  const int wid = tid >> 6;
  const int wm = wid >> 1, wn = wid & 1;
  const int l15 = lane & 15, l4 = lane >> 4;
  const int bm = blockIdx.y * TBM;
  const int bn = blockIdx.x * TBN;

  f32x4 acc[4][4];
#pragma unroll
  for (int i = 0; i < 4; ++i)
#pragma unroll
    for (int j = 0; j < 4; ++j) acc[i][j] = (f32x4){0.f, 0.f, 0.f, 0.f};

  for (int k0 = 0; k0 < K; k0 += TBK) {
    // stage A (fp32 -> hi/lo split on the fly)
#pragma unroll
    for (int it = 0; it < 4; ++it) {
      int f = tid + 256 * it;
      int row = f >> 3;
      int kq = (f & 7) << 2;
      const float* ap = A + (size_t)(bm + row) * lda + k0 + kq;
      float v0, v1, v2, v3;
      if (k0 + kq + 3 < K) {
        float4 t = *(const float4*)ap;
        v0 = t.x; v1 = t.y; v2 = t.z; v3 = t.w;
      } else {
        v0 = (k0 + kq + 0 < K) ? ap[0] : 0.f;
        v1 = (k0 + kq + 1 < K) ? ap[1] : 0.f;
        v2 = (k0 + kq + 2 < K) ? ap[2] : 0.f;
        v3 = (k0 + kq + 3 < K) ? ap[3] : 0.f;
      }
      ushort4 h, l;
      split2(v0, h.x, l.x); split2(v1, h.y, l.y);
      split2(v2, h.z, l.z); split2(v3, h.w, l.w);
      *(ushort4*)&Ah[row][kq] = h;
      *(ushort4*)&Al[row][kq] = l;
    }
    // stage B (pre-split planes)
#pragma unroll
    for (int it = 0; it < 2; ++it) {
      int c = tid + 256 * it;
      int row = c >> 2;
      int kq = (c & 3) << 3;
      int gn = bn + row;
      u16x8 vh = {0, 0, 0, 0, 0, 0, 0, 0};
      u16x8 vl = {0, 0, 0, 0, 0, 0, 0, 0};
      if (gn < N && k0 + kq < K) {
        vh = *(const u16x8*)(WH + (size_t)gn * K + k0 + kq);
        vl = *(const u16x8*)(WL + (size_t)gn * K + k0 + kq);
      }
      *(u16x8*)&Bh[row][kq] = vh;
      *(u16x8*)&Bl[row][kq] = vl;
    }
    __syncthreads();

    short8v ah[4], alo[4], bh[4], blo[4];
#pragma unroll
    for (int mf = 0; mf < 4; ++mf) {
      int r = wm * 64 + mf * 16 + l15;
      ah[mf]  = *(const short8v*)&Ah[r][l4 * 8];
      alo[mf] = *(const short8v*)&Al[r][l4 * 8];
    }
#pragma unroll
    for (int nf = 0; nf < 4; ++nf) {
      int r = wn * 64 + nf * 16 + l15;
      bh[nf]  = *(const short8v*)&Bh[r][l4 * 8];
      blo[nf] = *(const short8v*)&Bl[r][l4 * 8];
    }
#pragma unroll
    for (int mf = 0; mf < 4; ++mf)
#pragma unroll
      for (int nf = 0; nf < 4; ++nf) {
        acc[mf][nf] = __builtin_amdgcn_mfma_f32_16x16x32_bf16(ah[mf], bh[nf], acc[mf][nf], 0, 0, 0);
        acc[mf][nf] = __builtin_amdgcn_mfma_f32_16x16x32_bf16(ah[mf], blo[nf], acc[mf][nf], 0, 0, 0);
        acc[mf][nf] = __builtin_amdgcn_mfma_f32_16x16x32_bf16(alo[mf], bh[nf], acc[mf][nf], 0, 0, 0);
      }
    __syncthreads();
  }

  // epilogue: D row = (lane>>4)*4 + reg, col = lane&15  [m89-verified]
#pragma unroll
  for (int mf = 0; mf < 4; ++mf) {
#pragma unroll
    for (int nf = 0; nf < 4; ++nf) {
      int col = bn + wn * 64 + nf * 16 + l15;
      if (col < N) {
        float bv = (EPI >= 1) ? bias[col] : 0.f;
        int row0 = bm + wm * 64 + mf * 16 + l4 * 4;
#pragma unroll
        for (int r = 0; r < 4; ++r) {
          float v = acc[mf][nf][r] + bv;
          int row = row0 + r;
          if (EPI == 2) v += res[(size_t)row * ldr + col];
          if (EPI == 3) v = 0.5f * v * (1.0f + erff(v * 0.70710678118654752f));
          C[(size_t)row * N + col] = v;
        }
      }
    }
  }
}

// ---------------------------------------------------------------- fused flash attention (unchanged r4)
#define BI 64
#define BJ 32

__global__ __launch_bounds__(256) void fattn_kernel(const float* __restrict__ Q, const float* __restrict__ K,
                                                    const float* __restrict__ V, const float* __restrict__ Mm,
                                                    float* __restrict__ O, int N, int ldq) {
  __shared__ __align__(16) float Qst[DH][BI];
  __shared__ __align__(16) float KV[BJ * 104];
  __shared__ __align__(16) float Ss[BI][36];
  float (*Kst)[BJ]  = (float (*)[BJ])KV;
  float (*Vs)[104]  = (float (*)[104])KV;

  const int tid = threadIdx.x;
  const int tr = tid >> 4;
  const int tc = tid & 15;
  const int i0 = blockIdx.x * BI;
  const int h  = blockIdx.y;
  const int b  = blockIdx.z;

  const float* Qb = Q + (size_t)b * N * ldq + h * DH;
  const float* Kb = K + (size_t)b * N * ldq + h * DH;
  const float* Vb = V + (size_t)b * N * ldq + h * DH;

  for (int e = tid; e < (DH / 4) * BI; e += 256) {
    int c = e >> 6, r = e & 63;
    int gi = i0 + r; if (gi >= N) gi = N - 1;
    float4 v = *(const float4*)(Qb + (size_t)gi * ldq + 4 * c);
    Qst[4 * c + 0][r] = v.x; Qst[4 * c + 1][r] = v.y;
    Qst[4 * c + 2][r] = v.z; Qst[4 * c + 3][r] = v.w;
  }

  float m_i[4], l_i[4];
  float oa[4][4] = {};
  float ob[4][4] = {};
#pragma unroll
  for (int i = 0; i < 4; ++i) { m_i[i] = -INFINITY; l_i[i] = 0.f; }

  const int njt = (N + BJ - 1) / BJ;
  for (int jt = 0; jt < njt; ++jt) {
    const int j0 = jt * BJ;
    __syncthreads();
    for (int e = tid; e < (DH / 4) * BJ; e += 256) {
      int c = e >> 5, r = e & 31;
      int gj = j0 + r; if (gj >= N) gj = N - 1;
      float4 v = *(const float4*)(Kb + (size_t)gj * ldq + 4 * c);
      Kst[4 * c + 0][r] = v.x; Kst[4 * c + 1][r] = v.y;
      Kst[4 * c + 2][r] = v.z; Kst[4 * c + 3][r] = v.w;
    }
    __syncthreads();

    float sacc[4][2] = {};
#pragma unroll 4
    for (int kk = 0; kk < DH; ++kk) {
      float4 a   = *(const float4*)&Qst[kk][4 * tr];
      float2 kb2 = *(const float2*)&Kst[kk][2 * tc];
      sacc[0][0] += a.x * kb2.x; sacc[0][1] += a.x * kb2.y;
      sacc[1][0] += a.y * kb2.x; sacc[1][1] += a.y * kb2.y;
      sacc[2][0] += a.z * kb2.x; sacc[2][1] += a.z * kb2.y;
      sacc[3][0] += a.w * kb2.x; sacc[3][1] += a.w * kb2.y;
    }

    const float* Mbase = Mm + (size_t)b * N * N;
    const int c0 = j0 + 2 * tc;
#pragma unroll
    for (int i = 0; i < 4; ++i) {
      int gi = i0 + 4 * tr + i; if (gi >= N) gi = N - 1;
      const float* Mr = Mbase + (size_t)gi * N + c0;
      float mv0 = 0.f, mv1 = 0.f;
      if (c0 + 1 < N) { float2 m2 = *(const float2*)Mr; mv0 = m2.x; mv1 = m2.y; }
      else if (c0 < N) { mv0 = Mr[0]; }
      float s0 = (c0 < N)     ? sacc[i][0] * ATT_SCALE * (1.0f + mv0) : -INFINITY;
      float s1 = (c0 + 1 < N) ? sacc[i][1] * ATT_SCALE * (1.0f + mv1) : -INFINITY;
      float rm = fmaxf(s0, s1);
      rm = fmaxf(rm, __shfl_xor(rm, 1, 16));
      rm = fmaxf(rm, __shfl_xor(rm, 2, 16));
      rm = fmaxf(rm, __shfl_xor(rm, 4, 16));
      rm = fmaxf(rm, __shfl_xor(rm, 8, 16));
      float nm = fmaxf(m_i[i], rm);
      float f = expf(m_i[i] - nm);
      float p0 = expf(s0 - nm);
      float p1 = expf(s1 - nm);
      float ts = p0 + p1;
      ts += __shfl_xor(ts, 1, 16);
      ts += __shfl_xor(ts, 2, 16);
      ts += __shfl_xor(ts, 4, 16);
      ts += __shfl_xor(ts, 8, 16);
      l_i[i] = l_i[i] * f + ts;
      m_i[i] = nm;
#pragma unroll
      for (int q = 0; q < 4; ++q) { oa[i][q] *= f; ob[i][q] *= f; }
      *(float2*)&Ss[4 * tr + i][2 * tc] = make_float2(p0, p1);
    }
    __syncthreads();

    for (int e = tid; e < (DH / 4) * BJ; e += 256) {
      int c = e % 25, r = e / 25;
      int gj = j0 + r; if (gj >= N) gj = N - 1;
      *(float4*)&Vs[r][4 * c] = *(const float4*)(Vb + (size_t)gj * ldq + 4 * c);
    }
    __syncthreads();

#pragma unroll 2
    for (int jj = 0; jj < BJ / 4; ++jj) {
      float4 p0 = *(const float4*)&Ss[4 * tr + 0][4 * jj];
      float4 p1 = *(const float4*)&Ss[4 * tr + 1][4 * jj];
      float4 p2 = *(const float4*)&Ss[4 * tr + 2][4 * jj];
      float4 p3 = *(const float4*)&Ss[4 * tr + 3][4 * jj];
      float pv[4][4] = {{p0.x, p0.y, p0.z, p0.w}, {p1.x, p1.y, p1.z, p1.w},
                        {p2.x, p2.y, p2.z, p2.w}, {p3.x, p3.y, p3.z, p3.w}};
#pragma unroll
      for (int q = 0; q < 4; ++q) {
        int j = 4 * jj + q;
        float4 va = *(const float4*)&Vs[j][4 * tc];
        float4 vb = *(const float4*)&Vs[j][64 + 4 * tc];
#pragma unroll
        for (int i = 0; i < 4; ++i) {
          oa[i][0] += pv[i][q] * va.x; oa[i][1] += pv[i][q] * va.y;
          oa[i][2] += pv[i][q] * va.z; oa[i][3] += pv[i][q] * va.w;
          ob[i][0] += pv[i][q] * vb.x; ob[i][1] += pv[i][q] * vb.y;
          ob[i][2] += pv[i][q] * vb.z; ob[i][3] += pv[i][q] * vb.w;
        }
      }
    }
  }

  const int HD = HEADS * DH;
  float* Ob = O + (size_t)b * N * HD + h * DH;
#pragma unroll
  for (int i = 0; i < 4; ++i) {
    int gi = i0 + 4 * tr + i;
    if (gi < N) {
      float inv = 1.0f / l_i[i];
      float4 w = make_float4(oa[i][0] * inv, oa[i][1] * inv, oa[i][2] * inv, oa[i][3] * inv);
      *(float4*)(Ob + (size_t)gi * HD + 4 * tc) = w;
      if (tc < 9) {
        float4 w2 = make_float4(ob[i][0] * inv, ob[i][1] * inv, ob[i][2] * inv, ob[i][3] * inv);
        *(float4*)(Ob + (size_t)gi * HD + 64 + 4 * tc) = w2;
      }
    }
  }
}

// ---------------------------------------------------------------- layernorm
__global__ __launch_bounds__(128) void ln_kernel(const float* __restrict__ Y, const float* __restrict__ g,
                                                 const float* __restrict__ bta, float* __restrict__ X) {
  int row = blockIdx.x;
  const float* y = Y + (size_t)row * ROI;
  float* x = X + (size_t)row * ROI;
  int tid = threadIdx.x;
  __shared__ float red[128];
  float s = 0.f;
  for (int c = tid; c < ROI; c += 128) s += y[c];
  red[tid] = s; __syncthreads();
  for (int st = 64; st > 0; st >>= 1) { if (tid < st) red[tid] += red[tid + st]; __syncthreads(); }
  float mu = red[0] / ROI;
  __syncthreads();
  float v = 0.f;
  for (int c = tid; c < ROI; c += 128) { float d = y[c] - mu; v += d * d; }
  red[tid] = v; __syncthreads();
  for (int st = 64; st > 0; st >>= 1) { if (tid < st) red[tid] += red[tid + st]; __syncthreads(); }
  float rstd = rsqrtf(red[0] / ROI + 1e-5f);
  for (int c = tid; c < ROI; c += 128) x[c] = (y[c] - mu) * rstd * g[c] + bta[c];
}

// ---------------------------------------------------------------- classifier head
__global__ __launch_bounds__(128) void cls_kernel(const float* __restrict__ X, const float* __restrict__ r1w,
                                                  const float* __restrict__ r1b, const float* __restrict__ r2w,
                                                  const float* __restrict__ r2b, float* __restrict__ probs, int N) {
  int b = blockIdx.x, tid = threadIdx.x;
  __shared__ float gf[ROI];
  __shared__ float hid[128];
  for (int c = tid; c < ROI; c += 128) {
    float s = 0.f;
    for (int n = 0; n < N; ++n) s += X[((size_t)b * N + n) * ROI + c];
    gf[c] = s / (float)N;
  }
  __syncthreads();
  {
    float a = r1b[tid];
    for (int k = 0; k < ROI; ++k) a += gf[k] * r1w[k * 128 + tid];
    hid[tid] = (a >= 0.f) ? a : 0.01f * a;
  }
  __syncthreads();
  if (tid < NC) {
    float l = r2b[tid];
    for (int k = 0; k < 128; ++k) l += hid[k] * r2w[k * NC + tid];
    gf[tid] = l;
  }
  __syncthreads();
  if (tid == 0) {
    float m = fmaxf(gf[0], gf[1]);
    float e0 = expf(gf[0] - m), e1 = expf(gf[1] - m);
    float inv = 1.f / (e0 + e1);
    probs[b * NC + 0] = e0 * inv;
    probs[b * NC + 1] = e1 * inv;
  }
}

// ---------------------------------------------------------------- pooling
__global__ __launch_bounds__(128) void score_kernel(const float* __restrict__ M, const float* __restrict__ X,
                                                    const float* __restrict__ pws, const float* __restrict__ pwf,
                                                    const float* __restrict__ pmw, const float* __restrict__ pmb,
                                                    float* __restrict__ scores) {
  int i = blockIdx.x, b = blockIdx.y, tid = threadIdx.x;
  const float* mr = M + ((size_t)b * ROI + i) * ROI;
  const float* xr = X + ((size_t)b * ROI + i) * ROI;
  float s1 = 0.f, s2 = 0.f;
  for (int j = tid; j < ROI; j += 128) { s1 += mr[j] * pws[j]; s2 += xr[j] * pwf[j]; }
  __shared__ float r1[128], r2[128];
  r1[tid] = s1; r2[tid] = s2; __syncthreads();
  for (int st = 64; st > 0; st >>= 1) {
    if (tid < st) { r1[tid] += r1[tid + st]; r2[tid] += r2[tid + st]; }
    __syncthreads();
  }
  if (tid == 0) {
    float a = fabsf(r1[0]), c = fabsf(r2[0]);
    float z = a * pmw[0] + c * pmw[1] + pmb[0];
    scores[b * ROI + i] = 1.f / (1.f + expf(-z));
  }
}

__global__ __launch_bounds__(128) void select_kernel(const float* __restrict__ scores, int* __restrict__ idx) {
  int b = blockIdx.x, tid = threadIdx.x;
  __shared__ float sc[ROI];
  __shared__ int sel[ROI];
  for (int i = tid; i < ROI; i += 128) sc[i] = scores[b * ROI + i];
  __syncthreads();
  for (int i = tid; i < ROI; i += 128) {
    float si = sc[i];
    int rank = 0;
    for (int j = 0; j < ROI; ++j) {
      float sj = sc[j];
      rank += (sj > si) || (sj == si && j < i);
    }
    sel[i] = (rank < KPOOL) ? 1 : 0;
  }
  __syncthreads();
  for (int i = tid; i < ROI; i += 128) {
    if (sel[i]) {
      int pos = 0;
      for (int j = 0; j < i; ++j) pos += sel[j];
      idx[b * KPOOL + pos] = i;
    }
  }
}

__global__ __launch_bounds__(128) void gatherx_kernel(const float* __restrict__ X, const float* __restrict__ scores,
                                                      const int* __restrict__ idx, float* __restrict__ Xp) {
  int p = blockIdx.x % KPOOL, b = blockIdx.x / KPOOL, tid = threadIdx.x;
  int src = idx[b * KPOOL + p];
  float sw = scores[b * ROI + src];
  const float* xr = X + ((size_t)b * ROI + src) * ROI;
  float* o = Xp + ((size_t)b * KPOOL + p) * ROI;
  for (int c = tid; c < ROI; c += 128) o[c] = xr[c] * sw;
}

__global__ __launch_bounds__(128) void gatherm_kernel(const float* __restrict__ M, const int* __restrict__ idx,
                                                      float* __restrict__ Mp) {
  int p = blockIdx.x % KPOOL, b = blockIdx.x / KPOOL, tid = threadIdx.x;
  __shared__ int id[KPOOL];
  for (int q = tid; q < KPOOL; q += 128) id[q] = idx[b * KPOOL + q];
  __syncthreads();
  int src = idx[b * KPOOL + p];
  const float* mr = M + ((size_t)b * ROI + src) * ROI;
  float* o = Mp + ((size_t)b * KPOOL + p) * KPOOL;
  for (int q = tid; q < KPOOL; q += 128) o[q] = mr[id[q]];
}

// ---------------------------------------------------------------- final output
__global__ __launch_bounds__(128) void final_kernel(const float* __restrict__ X, const float* __restrict__ probs,
                                                    float* __restrict__ out, int N) {
  int b = blockIdx.x, tid = threadIdx.x;
  __shared__ float f[ROI];
  __shared__ float red[128];
  for (int c = tid; c < ROI; c += 128) {
    float s = 0.f;
    for (int n = 0; n < N; ++n) s += X[((size_t)b * N + n) * ROI + c];
    f[c] = s / (float)N;
  }
  __syncthreads();
  float ls = 0.f;
  for (int c = tid; c < ROI; c += 128) ls += f[c] * f[c];
  red[tid] = ls; __syncthreads();
  for (int st = 64; st > 0; st >>= 1) { if (tid < st) red[tid] += red[tid + st]; __syncthreads(); }
  float inv = 1.f / fmaxf(sqrtf(red[0]), 1e-12f);
  for (int c = tid; c < ROI; c += 128) out[b * ROI + c] = f[c] * inv;
  if (tid < NC) out[NB * ROI + b * NC + tid] = 0.5f * (probs[b * NC + tid] + probs[NB * NC + b * NC + tid]);
}

// ---------------------------------------------------------------- host orchestration
template<int EPI>
static inline void mgemm(const float* A, int lda, const unsigned short* WH, const unsigned short* WL,
                         const float* bias, const float* res, int ldr, float* C,
                         int M, int N, int K, hipStream_t st) {
  dim3 g((N + TBN - 1) / TBN, M / TBM);
  mgemm_kernel<EPI><<<g, 256, 0, st>>>(A, lda, WH, WL, bias, res, ldr, C, M, N, K);
}

static inline void packw(const float* W, int K, int N, unsigned short* WH, unsigned short* WL, hipStream_t st) {
  dim3 g((N + 63) / 64, (K + 63) / 64);
  packw_kernel<<<g, 256, 0, st>>>(W, K, N, WH, WL);
}

extern "C" void kernel_launch(void* const* d_in, const int* in_sizes, int n_in,
                              void* d_out, int out_size, void* d_ws, size_t ws_size,
                              hipStream_t stream) {
  const float* in  = (const float*)d_in[0];
  const float* sel = (const float*)d_in[1];
  const float* wq  = (const float*)d_in[2];
  const float* wk  = (const float*)d_in[3];
  const float* wv  = (const float*)d_in[4];
  const float* wo  = (const float*)d_in[5];
  const float* bo  = (const float*)d_in[6];
  const float* w1  = (const float*)d_in[7];
  const float* b1  = (const float*)d_in[8];
  const float* w2  = (const float*)d_in[9];
  const float* b2  = (const float*)d_in[10];
  const float* lng = (const float*)d_in[11];
  const float* lnb = (const float*)d_in[12];
  const float* pws = (const float*)d_in[13];
  const float* pwf = (const float*)d_in[14];
  const float* pmw = (const float*)d_in[15];
  const float* pmb = (const float*)d_in[16];
  const float* r1w = (const float*)d_in[17];
  const float* r1b = (const float*)d_in[18];
  const float* r2w = (const float*)d_in[19];
  const float* r2b = (const float*)d_in[20];
  float* out = (float*)d_out;

  float* ws = (float*)d_ws;
  const size_t AT = (size_t)NB * ROI * ROI;  // 10,240,000 floats

  // weight planes (u16) in [0, 1.28M floats) of slab 0
  unsigned short* up = (unsigned short*)ws;
  unsigned short* qkvH = up;                 // 1200x400
  unsigned short* qkvL = up + 480000;
  unsigned short* woH  = up + 960000;        // 400x400
  unsigned short* woL  = up + 1120000;
  unsigned short* w1H  = up + 1280000;       // 800x400
  unsigned short* w1L  = up + 1600000;
  unsigned short* w2H  = up + 1920000;       // 400x800
  unsigned short* w2L  = up + 2240000;

  float* Mmask = ws + AT;            // [1,2)
  float* QKV0  = ws + 2 * AT;        // [2,5)
  float* O0    = ws + 5 * AT;        // [5,6)
  float* Xa0   = ws + 2 * AT;        // [2,3)
  float* H0    = ws + 3 * AT;        // [3,5)
  float* Y0    = ws + 5 * AT;        // [5,6)
  float* Xn    = ws + 2 * AT;        // [2,3)
  float* Xp    = ws + 5 * AT;        // [5, 5.7)
  float* Mp    = ws + 4 * AT;        // [4, 4.49)
  float* QKV1  = ws + AT;            // [1, 3.1)
  float* O1    = ws + 31744000ULL;   // [3.1, 3.8)
  float* Xa1   = ws + AT;            // [1, 1.7)
  float* H1    = ws + 17408000ULL;   // [1.7, 3.1)
  float* Y1    = ws + 31744000ULL;   // [3.1, 3.8)
  float* Xf    = ws + 4 * AT;        // [4, 4.7)

  float* smalls = ws + 6 * AT;
  float* meanb = smalls;
  float* stdb  = smalls + 64;
  float* scores = smalls + 128;
  int*   idx = (int*)(smalls + 128 + NB * ROI);
  float* probs = smalls + 128 + NB * ROI + NB * KPOOL;

  pre_reduce_kernel<<<NB, 256, 0, stream>>>(in, meanb, stdb);
  build_m_kernel<<<(int)((AT + 255) / 256), 256, 0, stream>>>(in, sel, meanb, stdb, Mmask);

  // ---------------- depth 0: N=400 tokens, Mtok=25600, x = in (lda 800)
  {
    const int N = ROI;
    const int Mtok = NB * N;  // 25600
    packw(wq, ROI, ROI, qkvH + 0,      qkvL + 0,      stream);
    packw(wk, ROI, ROI, qkvH + 160000, qkvL + 160000, stream);
    packw(wv, ROI, ROI, qkvH + 320000, qkvL + 320000, stream);
    packw(wo, ROI, ROI, woH, woL, stream);
    packw(w1, ROI, HIDF, w1H, w1L, stream);
    packw(w2, HIDF, ROI, w2H, w2L, stream);

    mgemm<0>(in, 2 * ROI, qkvH, qkvL, nullptr, nullptr, 0, QKV0, Mtok, 3 * ROI, ROI, stream);
    fattn_kernel<<<dim3((N + BI - 1) / BI, HEADS, NB), 256, 0, stream>>>(
        QKV0, QKV0 + ROI, QKV0 + 2 * ROI, Mmask, O0, N, 3 * ROI);
    mgemm<2>(O0, ROI, woH, woL, bo, in, 2 * ROI, Xa0, Mtok, ROI, ROI, stream);
    mgemm<3>(Xa0, ROI, w1H, w1L, b1, nullptr, 0, H0, Mtok, HIDF, ROI, stream);
    mgemm<2>(H0, HIDF, w2H, w2L, b2, Xa0, ROI, Y0, Mtok, ROI, HIDF, stream);
    ln_kernel<<<Mtok, 128, 0, stream>>>(Y0, lng, lnb, Xn);
    cls_kernel<<<NB, 128, 0, stream>>>(Xn, r1w, r1b, r2w, r2b, probs, N);
    score_kernel<<<dim3(ROI, NB), 128, 0, stream>>>(Mmask, Xn, pws, pwf, pmw, pmb, scores);
    select_kernel<<<NB, 128, 0, stream>>>(scores, idx);
    gatherx_kernel<<<NB * KPOOL, 128, 0, stream>>>(Xn, scores, idx, Xp);
    gatherm_kernel<<<NB * KPOOL, 128, 0, stream>>>(Mmask, idx, Mp);
  }

  // ---------------- depth 1: N=280, Mtok=17920, x = Xp (lda 400)
  {
    const int N = KPOOL;
    const int Mtok = NB * N;  // 17920
    const int d = 1;
    const float* wq1 = wq + (size_t)d * ROI * ROI;
    const float* wk1 = wk + (size_t)d * ROI * ROI;
    const float* wv1 = wv + (size_t)d * ROI * ROI;
    const float* wo1 = wo + (size_t)d * ROI * ROI;
    const float* bo1 = bo + (size_t)d * ROI;
    const float* w11 = w1 + (size_t)d * ROI * HIDF;
    const float* b11 = b1 + (size_t)d * HIDF;
    const float* w21 = w2 + (size_t)d * HIDF * ROI;
    const float* b21 = b2 + (size_t)d * ROI;
    const float* lng1 = lng + (size_t)d * ROI;
    const float* lnb1 = lnb + (size_t)d * ROI;
    const float* r1w1 = r1w + (size_t)d * ROI * 128;
    const float* r1b1 = r1b + (size_t)d * 128;
    const float* r2w1 = r2w + (size_t)d * 128 * NC;
    const float* r2b1 = r2b + (size_t)d * NC;

    packw(wq1, ROI, ROI, qkvH + 0,      qkvL + 0,      stream);
    packw(wk1, ROI, ROI, qkvH + 160000, qkvL + 160000, stream);
    packw(wv1, ROI, ROI, qkvH + 320000, qkvL + 320000, stream);
    packw(wo1, ROI, ROI, woH, woL, stream);
    packw(w11, ROI, HIDF, w1H, w1L, stream);
    packw(w21, HIDF, ROI, w2H, w2L, stream);

    mgemm<0>(Xp, ROI, qkvH, qkvL, nullptr, nullptr, 0, QKV1, Mtok, 3 * ROI, ROI, stream);
    fattn_kernel<<<dim3((N + BI - 1) / BI, HEADS, NB), 256, 0, stream>>>(
        QKV1, QKV1 + ROI, QKV1 + 2 * ROI, Mp, O1, N, 3 * ROI);
    mgemm<2>(O1, ROI, woH, woL, bo1, Xp, ROI, Xa1, Mtok, ROI, ROI, stream);
    mgemm<3>(Xa1, ROI, w1H, w1L, b11, nullptr, 0, H1, Mtok, HIDF, ROI, stream);
    mgemm<2>(H1, HIDF, w2H, w2L, b21, Xa1, ROI, Y1, Mtok, ROI, HIDF, stream);
    ln_kernel<<<Mtok, 128, 0, stream>>>(Y1, lng1, lnb1, Xf);
    cls_kernel<<<NB, 128, 0, stream>>>(Xf, r1w1, r1b1, r2w1, r2b1, probs + NB * NC, N);
    final_kernel<<<NB, 128, 0, stream>>>(Xf, probs, out, N);
  }
  (void)in_sizes; (void)n_in; (void)out_size; (void)ws_size;
}

// Round 6
// 2619.453 us; speedup vs baseline: 1.3687x; 1.0548x over previous
//
#include <hip/hip_runtime.h>
#include <math.h>

#define ROI 400
#define HEADS 4
#define DH 100
#define NB 64
#define HIDF 800
#define NC 2
#define KPOOL 280
#define ATT_SCALE 0.1f

typedef __attribute__((ext_vector_type(8))) short short8v;
typedef __attribute__((ext_vector_type(8))) unsigned short u16x8;
typedef __attribute__((ext_vector_type(4))) float f32x4;

union U8 { short8v v; unsigned short u[8]; };

__device__ __forceinline__ unsigned short f2bf(float x) {
  unsigned int u = __float_as_uint(x);
  u += 0x7fffu + ((u >> 16) & 1u);
  return (unsigned short)(u >> 16);
}
__device__ __forceinline__ void split2(float x, unsigned short& h, unsigned short& l) {
  h = f2bf(x);
  float hf = __uint_as_float(((unsigned int)h) << 16);
  l = f2bf(x - hf);
}

// ---------------------------------------------------------------- preprocess
__global__ __launch_bounds__(256) void pre_reduce_kernel(const float* __restrict__ in,
                                                         float* __restrict__ meanb,
                                                         float* __restrict__ stdb) {
  int b = blockIdx.x;
  const float* p = in + (size_t)b * ROI * (2 * ROI);
  double s = 0.0, ss = 0.0;
  const int n = ROI * ROI;
  for (int e = threadIdx.x; e < n; e += blockDim.x) {
    int r = e / ROI, c = e % ROI;
    float v = log10f(p[(size_t)r * (2 * ROI) + ROI + c] + 1.0f);
    s += v; ss += (double)v * (double)v;
  }
  __shared__ double rs[256], rss[256];
  rs[threadIdx.x] = s; rss[threadIdx.x] = ss;
  __syncthreads();
  for (int st = 128; st > 0; st >>= 1) {
    if (threadIdx.x < st) { rs[threadIdx.x] += rs[threadIdx.x + st]; rss[threadIdx.x] += rss[threadIdx.x + st]; }
    __syncthreads();
  }
  if (threadIdx.x == 0) {
    double mean = rs[0] / n;
    double var = (rss[0] - rs[0] * rs[0] / n) / (double)(n - 1);
    meanb[b] = (float)mean;
    stdb[b]  = (float)(sqrt(var) + 1e-6);
  }
}

__global__ __launch_bounds__(256) void build_m_kernel(const float* __restrict__ in,
                                                      const float* __restrict__ sel,
                                                      const float* __restrict__ meanb,
                                                      const float* __restrict__ stdb,
                                                      float* __restrict__ M) {
  size_t e = (size_t)blockIdx.x * blockDim.x + threadIdx.x;
  const size_t total = (size_t)NB * ROI * ROI;
  if (e >= total) return;
  int c = (int)(e % ROI);
  int r = (int)((e / ROI) % ROI);
  int b = (int)(e / ((size_t)ROI * ROI));
  const float* row = in + ((size_t)b * ROI + r) * (2 * ROI);
  float v = log10f(row[ROI + c] + 1.0f);
  float sg = 1.0f / (1.0f + expf(-sel[r * ROI + c]));
  M[e] = ((v - meanb[b]) / stdb[b]) * sg;
}

// ---------------------------------------------------------------- weight pack: W[K][N] -> WT hi/lo [N][K]
__global__ __launch_bounds__(256) void packw_kernel(const float* __restrict__ W, int K, int N,
                                                    unsigned short* __restrict__ WH,
                                                    unsigned short* __restrict__ WL) {
  __shared__ float t[64][68];
  int bk = blockIdx.y * 64, bn = blockIdx.x * 64;
  int r = threadIdx.x >> 2;
  int c0 = (threadIdx.x & 3) << 4;
  int gk = bk + r;
#pragma unroll
  for (int i = 0; i < 4; ++i) {
    int c = c0 + 4 * i;
    float4 v = make_float4(0.f, 0.f, 0.f, 0.f);
    if (gk < K && bn + c < N) v = *(const float4*)(W + (size_t)gk * N + bn + c);
    *(float4*)&t[r][c] = v;
  }
  __syncthreads();
  int gn = bn + r;
#pragma unroll
  for (int i = 0; i < 4; ++i) {
    int c = c0 + 4 * i;      // k-local
    int gkk = bk + c;
    if (gn < N && gkk < K) {
      ushort4 h, l;
      split2(t[c + 0][r], h.x, l.x);
      split2(t[c + 1][r], h.y, l.y);
      split2(t[c + 2][r], h.z, l.z);
      split2(t[c + 3][r], h.w, l.w);
      *(ushort4*)(WH + (size_t)gn * K + gkk) = h;
      *(ushort4*)(WL + (size_t)gn * K + gkk) = l;
    }
  }
}

// ---------------------------------------------------------------- MFMA split-bf16 GEMM
#define TBM 128
#define TBN 128
#define TBK 32
#define KP 40

template<int EPI>
__global__ __launch_bounds__(256) void mgemm_kernel(const float* __restrict__ A, int lda,
                                                    const unsigned short* __restrict__ WH,
                                                    const unsigned short* __restrict__ WL,
                                                    const float* __restrict__ bias,
                                                    const float* __restrict__ res, int ldr,
                                                    float* __restrict__ C, int M, int N, int K) {
  __shared__ unsigned short Ah[TBM][KP], Al[TBM][KP], Bh[TBN][KP], Bl[TBN][KP];
  const int tid = threadIdx.x;
  const int lane = tid & 63;
  const int wid = tid >> 6;
  const int wm = wid >> 1, wn = wid & 1;
  const int l15 = lane & 15, l4 = lane >> 4;
  const int bm = blockIdx.y * TBM;
  const int bn = blockIdx.x * TBN;

  f32x4 acc[4][4];
#pragma unroll
  for (int i = 0; i < 4; ++i)
#pragma unroll
    for (int j = 0; j < 4; ++j) acc[i][j] = (f32x4){0.f, 0.f, 0.f, 0.f};

  for (int k0 = 0; k0 < K; k0 += TBK) {
#pragma unroll
    for (int it = 0; it < 4; ++it) {
      int f = tid + 256 * it;
      int row = f >> 3;
      int kq = (f & 7) << 2;
      const float* ap = A + (size_t)(bm + row) * lda + k0 + kq;
      float v0, v1, v2, v3;
      if (k0 + kq + 3 < K) {
        float4 t = *(const float4*)ap;
        v0 = t.x; v1 = t.y; v2 = t.z; v3 = t.w;
      } else {
        v0 = (k0 + kq + 0 < K) ? ap[0] : 0.f;
        v1 = (k0 + kq + 1 < K) ? ap[1] : 0.f;
        v2 = (k0 + kq + 2 < K) ? ap[2] : 0.f;
        v3 = (k0 + kq + 3 < K) ? ap[3] : 0.f;
      }
      ushort4 h, l;
      split2(v0, h.x, l.x); split2(v1, h.y, l.y);
      split2(v2, h.z, l.z); split2(v3, h.w, l.w);
      *(ushort4*)&Ah[row][kq] = h;
      *(ushort4*)&Al[row][kq] = l;
    }
#pragma unroll
    for (int it = 0; it < 2; ++it) {
      int c = tid + 256 * it;
      int row = c >> 2;
      int kq = (c & 3) << 3;
      int gn = bn + row;
      u16x8 vh = {0, 0, 0, 0, 0, 0, 0, 0};
      u16x8 vl = {0, 0, 0, 0, 0, 0, 0, 0};
      if (gn < N && k0 + kq < K) {
        vh = *(const u16x8*)(WH + (size_t)gn * K + k0 + kq);
        vl = *(const u16x8*)(WL + (size_t)gn * K + k0 + kq);
      }
      *(u16x8*)&Bh[row][kq] = vh;
      *(u16x8*)&Bl[row][kq] = vl;
    }
    __syncthreads();

    short8v ah[4], alo[4], bh[4], blo[4];
#pragma unroll
    for (int mf = 0; mf < 4; ++mf) {
      int r = wm * 64 + mf * 16 + l15;
      ah[mf]  = *(const short8v*)&Ah[r][l4 * 8];
      alo[mf] = *(const short8v*)&Al[r][l4 * 8];
    }
#pragma unroll
    for (int nf = 0; nf < 4; ++nf) {
      int r = wn * 64 + nf * 16 + l15;
      bh[nf]  = *(const short8v*)&Bh[r][l4 * 8];
      blo[nf] = *(const short8v*)&Bl[r][l4 * 8];
    }
#pragma unroll
    for (int mf = 0; mf < 4; ++mf)
#pragma unroll
      for (int nf = 0; nf < 4; ++nf) {
        acc[mf][nf] = __builtin_amdgcn_mfma_f32_16x16x32_bf16(ah[mf], bh[nf], acc[mf][nf], 0, 0, 0);
        acc[mf][nf] = __builtin_amdgcn_mfma_f32_16x16x32_bf16(ah[mf], blo[nf], acc[mf][nf], 0, 0, 0);
        acc[mf][nf] = __builtin_amdgcn_mfma_f32_16x16x32_bf16(alo[mf], bh[nf], acc[mf][nf], 0, 0, 0);
      }
    __syncthreads();
  }

#pragma unroll
  for (int mf = 0; mf < 4; ++mf) {
#pragma unroll
    for (int nf = 0; nf < 4; ++nf) {
      int col = bn + wn * 64 + nf * 16 + l15;
      if (col < N) {
        float bv = (EPI >= 1) ? bias[col] : 0.f;
        int row0 = bm + wm * 64 + mf * 16 + l4 * 4;
#pragma unroll
        for (int r = 0; r < 4; ++r) {
          float v = acc[mf][nf][r] + bv;
          int row = row0 + r;
          if (EPI == 2) v += res[(size_t)row * ldr + col];
          if (EPI == 3) v = 0.5f * v * (1.0f + erff(v * 0.70710678118654752f));
          C[(size_t)row * N + col] = v;
        }
      }
    }
  }
}

// ---------------------------------------------------------------- MFMA flash attention
// block = 256 thr (4 waves), 64 q rows of one (b,h); 32-kv tiles; split-bf16, 3-term mfma.
#define FBJ 32

__global__ __launch_bounds__(256) void fattn_kernel(const float* __restrict__ Q, const float* __restrict__ Kg,
                                                    const float* __restrict__ Vg, const float* __restrict__ Mm,
                                                    float* __restrict__ O, int N, int ldq) {
  __shared__ unsigned short Kh[FBJ][136], Kl[FBJ][136];   // [kv][d pad 128->136]
  __shared__ unsigned short Vth[112][40], Vtl[112][40];   // [d pad 112][kv pad 40]
  __shared__ unsigned short Ph[64][40], Pl[64][40];       // [q][kv pad 40]

  const int tid = threadIdx.x;
  const int lane = tid & 63;
  const int w = tid >> 6;
  const int l15 = lane & 15, l4 = lane >> 4;
  const int i0 = blockIdx.x * 64;
  const int h = blockIdx.y, b = blockIdx.z;
  const int HD = HEADS * DH;

  const float* Qb = Q + (size_t)b * N * ldq + h * DH;
  const float* Kb = Kg + (size_t)b * N * ldq + h * DH;
  const float* Vb = Vg + (size_t)b * N * ldq + h * DH;
  const float* Mb = Mm + (size_t)b * N * N;

  // zero V pad rows d=100..111 (never overwritten)
  for (int e = tid; e < 12 * 40; e += 256) {
    Vth[100 + e / 40][e % 40] = 0; Vtl[100 + e / 40][e % 40] = 0;
  }

  // Q A-fragments in registers: row m=l15 -> q = i0+16w+l15 ; k = kg*32 + l4*8 + j
  int qr = i0 + 16 * w + l15; if (qr >= N) qr = N - 1;
  const float* qrow = Qb + (size_t)qr * ldq;
  short8v qh[4], ql[4];
#pragma unroll
  for (int kg = 0; kg < 4; ++kg) {
    U8 th, tl;
#pragma unroll
    for (int j = 0; j < 8; ++j) {
      int d = kg * 32 + l4 * 8 + j;
      float v = (d < DH) ? qrow[d] : 0.f;
      split2(v, th.u[j], tl.u[j]);
    }
    qh[kg] = th.v; ql[kg] = tl.v;
  }

  float m_i[4], l_i[4];
  f32x4 o[7];
#pragma unroll
  for (int r = 0; r < 4; ++r) { m_i[r] = -INFINITY; l_i[r] = 0.f; }
#pragma unroll
  for (int ff = 0; ff < 7; ++ff) o[ff] = (f32x4){0.f, 0.f, 0.f, 0.f};

  const int njt = (N + FBJ - 1) / FBJ;
  for (int jt = 0; jt < njt; ++jt) {
    const int j0 = jt * FBJ;
    __syncthreads();   // prev tile's PV reads done before restage
    // stage K split: [kv][0..127], zero d>=100
    for (int e = tid; e < 32 * 32; e += 256) {
      int kv = e >> 5;
      int dq = (e & 31) << 2;
      int gj = j0 + kv; if (gj >= N) gj = N - 1;
      float4 t = make_float4(0.f, 0.f, 0.f, 0.f);
      if (dq + 3 < DH) t = *(const float4*)(Kb + (size_t)gj * ldq + dq);
      ushort4 hh, ll;
      split2(t.x, hh.x, ll.x); split2(t.y, hh.y, ll.y);
      split2(t.z, hh.z, ll.z); split2(t.w, hh.w, ll.w);
      *(ushort4*)&Kh[kv][dq] = hh;
      *(ushort4*)&Kl[kv][dq] = ll;
    }
    // stage V transposed split: Vt[d][kv]
    for (int e = tid; e < 32 * 25; e += 256) {
      int kv = e / 25;
      int dq = (e % 25) << 2;
      int gj = j0 + kv; if (gj >= N) gj = N - 1;
      float4 t = *(const float4*)(Vb + (size_t)gj * ldq + dq);
      ushort4 hh, ll;
      split2(t.x, hh.x, ll.x); split2(t.y, hh.y, ll.y);
      split2(t.z, hh.z, ll.z); split2(t.w, hh.w, ll.w);
      Vth[dq + 0][kv] = hh.x; Vtl[dq + 0][kv] = ll.x;
      Vth[dq + 1][kv] = hh.y; Vtl[dq + 1][kv] = ll.y;
      Vth[dq + 2][kv] = hh.z; Vtl[dq + 2][kv] = ll.z;
      Vth[dq + 3][kv] = hh.w; Vtl[dq + 3][kv] = ll.w;
    }
    __syncthreads();

    // QK^T: C[q 16][kv 32] = 2 frags
    f32x4 sacc[2];
    sacc[0] = (f32x4){0.f, 0.f, 0.f, 0.f};
    sacc[1] = (f32x4){0.f, 0.f, 0.f, 0.f};
#pragma unroll
    for (int kg = 0; kg < 4; ++kg) {
#pragma unroll
      for (int f = 0; f < 2; ++f) {
        short8v bh = *(const short8v*)&Kh[l15 + 16 * f][kg * 32 + l4 * 8];
        short8v bl = *(const short8v*)&Kl[l15 + 16 * f][kg * 32 + l4 * 8];
        sacc[f] = __builtin_amdgcn_mfma_f32_16x16x32_bf16(qh[kg], bh, sacc[f], 0, 0, 0);
        sacc[f] = __builtin_amdgcn_mfma_f32_16x16x32_bf16(qh[kg], bl, sacc[f], 0, 0, 0);
        sacc[f] = __builtin_amdgcn_mfma_f32_16x16x32_bf16(ql[kg], bh, sacc[f], 0, 0, 0);
      }
    }

    // softmax (C layout: q = l4*4+r, kv = l15+16f), write P split to LDS
    const int kv0 = j0 + l15, kv1 = j0 + l15 + 16;
#pragma unroll
    for (int r = 0; r < 4; ++r) {
      int gq = i0 + 16 * w + l4 * 4 + r;
      int gqc = (gq < N) ? gq : N - 1;
      const float* Mr = Mb + (size_t)gqc * N;
      float s0 = -INFINITY, s1 = -INFINITY;
      if (kv0 < N) s0 = sacc[0][r] * ATT_SCALE * (1.0f + Mr[kv0]);
      if (kv1 < N) s1 = sacc[1][r] * ATT_SCALE * (1.0f + Mr[kv1]);
      float rm = fmaxf(s0, s1);
      rm = fmaxf(rm, __shfl_xor(rm, 1, 16));
      rm = fmaxf(rm, __shfl_xor(rm, 2, 16));
      rm = fmaxf(rm, __shfl_xor(rm, 4, 16));
      rm = fmaxf(rm, __shfl_xor(rm, 8, 16));
      float nm = fmaxf(m_i[r], rm);
      float fr = expf(m_i[r] - nm);
      float p0 = (kv0 < N) ? expf(s0 - nm) : 0.f;
      float p1 = (kv1 < N) ? expf(s1 - nm) : 0.f;
      float ts = p0 + p1;
      ts += __shfl_xor(ts, 1, 16);
      ts += __shfl_xor(ts, 2, 16);
      ts += __shfl_xor(ts, 4, 16);
      ts += __shfl_xor(ts, 8, 16);
      l_i[r] = l_i[r] * fr + ts;
      m_i[r] = nm;
#pragma unroll
      for (int ff = 0; ff < 7; ++ff) o[ff][r] *= fr;
      unsigned short h0, l0, h1, l1;
      split2(p0, h0, l0); split2(p1, h1, l1);
      int prow = 16 * w + l4 * 4 + r;
      Ph[prow][l15] = h0;      Pl[prow][l15] = l0;
      Ph[prow][l15 + 16] = h1; Pl[prow][l15 + 16] = l1;
    }
    __syncthreads();   // P visible (and Vt staged)

    // PV: A = P [q 16][kv 32], B = Vt -> C[q][d] frags
    short8v ph = *(const short8v*)&Ph[16 * w + l15][l4 * 8];
    short8v pl = *(const short8v*)&Pl[16 * w + l15][l4 * 8];
#pragma unroll
    for (int ff = 0; ff < 7; ++ff) {
      short8v vh = *(const short8v*)&Vth[ff * 16 + l15][l4 * 8];
      short8v vl = *(const short8v*)&Vtl[ff * 16 + l15][l4 * 8];
      o[ff] = __builtin_amdgcn_mfma_f32_16x16x32_bf16(ph, vh, o[ff], 0, 0, 0);
      o[ff] = __builtin_amdgcn_mfma_f32_16x16x32_bf16(ph, vl, o[ff], 0, 0, 0);
      o[ff] = __builtin_amdgcn_mfma_f32_16x16x32_bf16(pl, vh, o[ff], 0, 0, 0);
    }
  }

  // epilogue: O[q][d] = o / l_i
  float* Ob = O + (size_t)b * N * HD + h * DH;
#pragma unroll
  for (int r = 0; r < 4; ++r) {
    int gq = i0 + 16 * w + l4 * 4 + r;
    if (gq < N) {
      float inv = 1.0f / l_i[r];
#pragma unroll
      for (int ff = 0; ff < 7; ++ff) {
        int d = ff * 16 + l15;
        if (d < DH) Ob[(size_t)gq * HD + d] = o[ff][r] * inv;
      }
    }
  }
}

// ---------------------------------------------------------------- layernorm
__global__ __launch_bounds__(128) void ln_kernel(const float* __restrict__ Y, const float* __restrict__ g,
                                                 const float* __restrict__ bta, float* __restrict__ X) {
  int row = blockIdx.x;
  const float* y = Y + (size_t)row * ROI;
  float* x = X + (size_t)row * ROI;
  int tid = threadIdx.x;
  __shared__ float red[128];
  float s = 0.f;
  for (int c = tid; c < ROI; c += 128) s += y[c];
  red[tid] = s; __syncthreads();
  for (int st = 64; st > 0; st >>= 1) { if (tid < st) red[tid] += red[tid + st]; __syncthreads(); }
  float mu = red[0] / ROI;
  __syncthreads();
  float v = 0.f;
  for (int c = tid; c < ROI; c += 128) { float d = y[c] - mu; v += d * d; }
  red[tid] = v; __syncthreads();
  for (int st = 64; st > 0; st >>= 1) { if (tid < st) red[tid] += red[tid + st]; __syncthreads(); }
  float rstd = rsqrtf(red[0] / ROI + 1e-5f);
  for (int c = tid; c < ROI; c += 128) x[c] = (y[c] - mu) * rstd * g[c] + bta[c];
}

// ---------------------------------------------------------------- classifier head
__global__ __launch_bounds__(128) void cls_kernel(const float* __restrict__ X, const float* __restrict__ r1w,
                                                  const float* __restrict__ r1b, const float* __restrict__ r2w,
                                                  const float* __restrict__ r2b, float* __restrict__ probs, int N) {
  int b = blockIdx.x, tid = threadIdx.x;
  __shared__ float gf[ROI];
  __shared__ float hid[128];
  for (int c = tid; c < ROI; c += 128) {
    float s = 0.f;
    for (int n = 0; n < N; ++n) s += X[((size_t)b * N + n) * ROI + c];
    gf[c] = s / (float)N;
  }
  __syncthreads();
  {
    float a = r1b[tid];
    for (int k = 0; k < ROI; ++k) a += gf[k] * r1w[k * 128 + tid];
    hid[tid] = (a >= 0.f) ? a : 0.01f * a;
  }
  __syncthreads();
  if (tid < NC) {
    float l = r2b[tid];
    for (int k = 0; k < 128; ++k) l += hid[k] * r2w[k * NC + tid];
    gf[tid] = l;
  }
  __syncthreads();
  if (tid == 0) {
    float m = fmaxf(gf[0], gf[1]);
    float e0 = expf(gf[0] - m), e1 = expf(gf[1] - m);
    float inv = 1.f / (e0 + e1);
    probs[b * NC + 0] = e0 * inv;
    probs[b * NC + 1] = e1 * inv;
  }
}

// ---------------------------------------------------------------- pooling
__global__ __launch_bounds__(128) void score_kernel(const float* __restrict__ M, const float* __restrict__ X,
                                                    const float* __restrict__ pws, const float* __restrict__ pwf,
                                                    const float* __restrict__ pmw, const float* __restrict__ pmb,
                                                    float* __restrict__ scores) {
  int i = blockIdx.x, b = blockIdx.y, tid = threadIdx.x;
  const float* mr = M + ((size_t)b * ROI + i) * ROI;
  const float* xr = X + ((size_t)b * ROI + i) * ROI;
  float s1 = 0.f, s2 = 0.f;
  for (int j = tid; j < ROI; j += 128) { s1 += mr[j] * pws[j]; s2 += xr[j] * pwf[j]; }
  __shared__ float r1[128], r2[128];
  r1[tid] = s1; r2[tid] = s2; __syncthreads();
  for (int st = 64; st > 0; st >>= 1) {
    if (tid < st) { r1[tid] += r1[tid + st]; r2[tid] += r2[tid + st]; }
    __syncthreads();
  }
  if (tid == 0) {
    float a = fabsf(r1[0]), c = fabsf(r2[0]);
    float z = a * pmw[0] + c * pmw[1] + pmb[0];
    scores[b * ROI + i] = 1.f / (1.f + expf(-z));
  }
}

__global__ __launch_bounds__(128) void select_kernel(const float* __restrict__ scores, int* __restrict__ idx) {
  int b = blockIdx.x, tid = threadIdx.x;
  __shared__ float sc[ROI];
  __shared__ int sel[ROI];
  for (int i = tid; i < ROI; i += 128) sc[i] = scores[b * ROI + i];
  __syncthreads();
  for (int i = tid; i < ROI; i += 128) {
    float si = sc[i];
    int rank = 0;
    for (int j = 0; j < ROI; ++j) {
      float sj = sc[j];
      rank += (sj > si) || (sj == si && j < i);
    }
    sel[i] = (rank < KPOOL) ? 1 : 0;
  }
  __syncthreads();
  for (int i = tid; i < ROI; i += 128) {
    if (sel[i]) {
      int pos = 0;
      for (int j = 0; j < i; ++j) pos += sel[j];
      idx[b * KPOOL + pos] = i;
    }
  }
}

__global__ __launch_bounds__(128) void gatherx_kernel(const float* __restrict__ X, const float* __restrict__ scores,
                                                      const int* __restrict__ idx, float* __restrict__ Xp) {
  int p = blockIdx.x % KPOOL, b = blockIdx.x / KPOOL, tid = threadIdx.x;
  int src = idx[b * KPOOL + p];
  float sw = scores[b * ROI + src];
  const float* xr = X + ((size_t)b * ROI + src) * ROI;
  float* o = Xp + ((size_t)b * KPOOL + p) * ROI;
  for (int c = tid; c < ROI; c += 128) o[c] = xr[c] * sw;
}

__global__ __launch_bounds__(128) void gatherm_kernel(const float* __restrict__ M, const int* __restrict__ idx,
                                                      float* __restrict__ Mp) {
  int p = blockIdx.x % KPOOL, b = blockIdx.x / KPOOL, tid = threadIdx.x;
  __shared__ int id[KPOOL];
  for (int q = tid; q < KPOOL; q += 128) id[q] = idx[b * KPOOL + q];
  __syncthreads();
  int src = idx[b * KPOOL + p];
  const float* mr = M + ((size_t)b * ROI + src) * ROI;
  float* o = Mp + ((size_t)b * KPOOL + p) * KPOOL;
  for (int q = tid; q < KPOOL; q += 128) o[q] = mr[id[q]];
}

// ---------------------------------------------------------------- final output
__global__ __launch_bounds__(128) void final_kernel(const float* __restrict__ X, const float* __restrict__ probs,
                                                    float* __restrict__ out, int N) {
  int b = blockIdx.x, tid = threadIdx.x;
  __shared__ float f[ROI];
  __shared__ float red[128];
  for (int c = tid; c < ROI; c += 128) {
    float s = 0.f;
    for (int n = 0; n < N; ++n) s += X[((size_t)b * N + n) * ROI + c];
    f[c] = s / (float)N;
  }
  __syncthreads();
  float ls = 0.f;
  for (int c = tid; c < ROI; c += 128) ls += f[c] * f[c];
  red[tid] = ls; __syncthreads();
  for (int st = 64; st > 0; st >>= 1) { if (tid < st) red[tid] += red[tid + st]; __syncthreads(); }
  float inv = 1.f / fmaxf(sqrtf(red[0]), 1e-12f);
  for (int c = tid; c < ROI; c += 128) out[b * ROI + c] = f[c] * inv;
  if (tid < NC) out[NB * ROI + b * NC + tid] = 0.5f * (probs[b * NC + tid] + probs[NB * NC + b * NC + tid]);
}

// ---------------------------------------------------------------- host orchestration
template<int EPI>
static inline void mgemm(const float* A, int lda, const unsigned short* WH, const unsigned short* WL,
                         const float* bias, const float* res, int ldr, float* C,
                         int M, int N, int K, hipStream_t st) {
  dim3 g((N + TBN - 1) / TBN, M / TBM);
  mgemm_kernel<EPI><<<g, 256, 0, st>>>(A, lda, WH, WL, bias, res, ldr, C, M, N, K);
}

static inline void packw(const float* W, int K, int N, unsigned short* WH, unsigned short* WL, hipStream_t st) {
  dim3 g((N + 63) / 64, (K + 63) / 64);
  packw_kernel<<<g, 256, 0, st>>>(W, K, N, WH, WL);
}

extern "C" void kernel_launch(void* const* d_in, const int* in_sizes, int n_in,
                              void* d_out, int out_size, void* d_ws, size_t ws_size,
                              hipStream_t stream) {
  const float* in  = (const float*)d_in[0];
  const float* sel = (const float*)d_in[1];
  const float* wq  = (const float*)d_in[2];
  const float* wk  = (const float*)d_in[3];
  const float* wv  = (const float*)d_in[4];
  const float* wo  = (const float*)d_in[5];
  const float* bo  = (const float*)d_in[6];
  const float* w1  = (const float*)d_in[7];
  const float* b1  = (const float*)d_in[8];
  const float* w2  = (const float*)d_in[9];
  const float* b2  = (const float*)d_in[10];
  const float* lng = (const float*)d_in[11];
  const float* lnb = (const float*)d_in[12];
  const float* pws = (const float*)d_in[13];
  const float* pwf = (const float*)d_in[14];
  const float* pmw = (const float*)d_in[15];
  const float* pmb = (const float*)d_in[16];
  const float* r1w = (const float*)d_in[17];
  const float* r1b = (const float*)d_in[18];
  const float* r2w = (const float*)d_in[19];
  const float* r2b = (const float*)d_in[20];
  float* out = (float*)d_out;

  float* ws = (float*)d_ws;
  const size_t AT = (size_t)NB * ROI * ROI;  // 10,240,000 floats

  unsigned short* up = (unsigned short*)ws;
  unsigned short* qkvH = up;                 // 1200x400
  unsigned short* qkvL = up + 480000;
  unsigned short* woH  = up + 960000;        // 400x400
  unsigned short* woL  = up + 1120000;
  unsigned short* w1H  = up + 1280000;       // 800x400
  unsigned short* w1L  = up + 1600000;
  unsigned short* w2H  = up + 1920000;       // 400x800
  unsigned short* w2L  = up + 2240000;

  float* Mmask = ws + AT;            // [1,2)
  float* QKV0  = ws + 2 * AT;        // [2,5)
  float* O0    = ws + 5 * AT;        // [5,6)
  float* Xa0   = ws + 2 * AT;        // [2,3)
  float* H0    = ws + 3 * AT;        // [3,5)
  float* Y0    = ws + 5 * AT;        // [5,6)
  float* Xn    = ws + 2 * AT;        // [2,3)
  float* Xp    = ws + 5 * AT;        // [5, 5.7)
  float* Mp    = ws + 4 * AT;        // [4, 4.49)
  float* QKV1  = ws + AT;            // [1, 3.1)
  float* O1    = ws + 31744000ULL;   // [3.1, 3.8)
  float* Xa1   = ws + AT;            // [1, 1.7)
  float* H1    = ws + 17408000ULL;   // [1.7, 3.1)
  float* Y1    = ws + 31744000ULL;   // [3.1, 3.8)
  float* Xf    = ws + 4 * AT;        // [4, 4.7)

  float* smalls = ws + 6 * AT;
  float* meanb = smalls;
  float* stdb  = smalls + 64;
  float* scores = smalls + 128;
  int*   idx = (int*)(smalls + 128 + NB * ROI);
  float* probs = smalls + 128 + NB * ROI + NB * KPOOL;

  pre_reduce_kernel<<<NB, 256, 0, stream>>>(in, meanb, stdb);
  build_m_kernel<<<(int)((AT + 255) / 256), 256, 0, stream>>>(in, sel, meanb, stdb, Mmask);

  // ---------------- depth 0: N=400 tokens, Mtok=25600, x = in (lda 800)
  {
    const int N = ROI;
    const int Mtok = NB * N;  // 25600
    packw(wq, ROI, ROI, qkvH + 0,      qkvL + 0,      stream);
    packw(wk, ROI, ROI, qkvH + 160000, qkvL + 160000, stream);
    packw(wv, ROI, ROI, qkvH + 320000, qkvL + 320000, stream);
    packw(wo, ROI, ROI, woH, woL, stream);
    packw(w1, ROI, HIDF, w1H, w1L, stream);
    packw(w2, HIDF, ROI, w2H, w2L, stream);

    mgemm<0>(in, 2 * ROI, qkvH, qkvL, nullptr, nullptr, 0, QKV0, Mtok, 3 * ROI, ROI, stream);
    fattn_kernel<<<dim3((N + 63) / 64, HEADS, NB), 256, 0, stream>>>(
        QKV0, QKV0 + ROI, QKV0 + 2 * ROI, Mmask, O0, N, 3 * ROI);
    mgemm<2>(O0, ROI, woH, woL, bo, in, 2 * ROI, Xa0, Mtok, ROI, ROI, stream);
    mgemm<3>(Xa0, ROI, w1H, w1L, b1, nullptr, 0, H0, Mtok, HIDF, ROI, stream);
    mgemm<2>(H0, HIDF, w2H, w2L, b2, Xa0, ROI, Y0, Mtok, ROI, HIDF, stream);
    ln_kernel<<<Mtok, 128, 0, stream>>>(Y0, lng, lnb, Xn);
    cls_kernel<<<NB, 128, 0, stream>>>(Xn, r1w, r1b, r2w, r2b, probs, N);
    score_kernel<<<dim3(ROI, NB), 128, 0, stream>>>(Mmask, Xn, pws, pwf, pmw, pmb, scores);
    select_kernel<<<NB, 128, 0, stream>>>(scores, idx);
    gatherx_kernel<<<NB * KPOOL, 128, 0, stream>>>(Xn, scores, idx, Xp);
    gatherm_kernel<<<NB * KPOOL, 128, 0, stream>>>(Mmask, idx, Mp);
  }

  // ---------------- depth 1: N=280, Mtok=17920, x = Xp (lda 400)
  {
    const int N = KPOOL;
    const int Mtok = NB * N;  // 17920
    const int d = 1;
    const float* wq1 = wq + (size_t)d * ROI * ROI;
    const float* wk1 = wk + (size_t)d * ROI * ROI;
    const float* wv1 = wv + (size_t)d * ROI * ROI;
    const float* wo1 = wo + (size_t)d * ROI * ROI;
    const float* bo1 = bo + (size_t)d * ROI;
    const float* w11 = w1 + (size_t)d * ROI * HIDF;
    const float* b11 = b1 + (size_t)d * HIDF;
    const float* w21 = w2 + (size_t)d * HIDF * ROI;
    const float* b21 = b2 + (size_t)d * ROI;
    const float* lng1 = lng + (size_t)d * ROI;
    const float* lnb1 = lnb + (size_t)d * ROI;
    const float* r1w1 = r1w + (size_t)d * ROI * 128;
    const float* r1b1 = r1b + (size_t)d * 128;
    const float* r2w1 = r2w + (size_t)d * 128 * NC;
    const float* r2b1 = r2b + (size_t)d * NC;

    packw(wq1, ROI, ROI, qkvH + 0,      qkvL + 0,      stream);
    packw(wk1, ROI, ROI, qkvH + 160000, qkvL + 160000, stream);
    packw(wv1, ROI, ROI, qkvH + 320000, qkvL + 320000, stream);
    packw(wo1, ROI, ROI, woH, woL, stream);
    packw(w11, ROI, HIDF, w1H, w1L, stream);
    packw(w21, HIDF, ROI, w2H, w2L, stream);

    mgemm<0>(Xp, ROI, qkvH, qkvL, nullptr, nullptr, 0, QKV1, Mtok, 3 * ROI, ROI, stream);
    fattn_kernel<<<dim3((N + 63) / 64, HEADS, NB), 256, 0, stream>>>(
        QKV1, QKV1 + ROI, QKV1 + 2 * ROI, Mp, O1, N, 3 * ROI);
    mgemm<2>(O1, ROI, woH, woL, bo1, Xp, ROI, Xa1, Mtok, ROI, ROI, stream);
    mgemm<3>(Xa1, ROI, w1H, w1L, b11, nullptr, 0, H1, Mtok, HIDF, ROI, stream);
    mgemm<2>(H1, HIDF, w2H, w2L, b21, Xa1, ROI, Y1, Mtok, ROI, HIDF, stream);
    ln_kernel<<<Mtok, 128, 0, stream>>>(Y1, lng1, lnb1, Xf);
    cls_kernel<<<NB, 128, 0, stream>>>(Xf, r1w1, r1b1, r2w1, r2b1, probs + NB * NC, N);
    final_kernel<<<NB, 128, 0, stream>>>(Xf, probs, out, N);
  }
  (void)in_sizes; (void)n_in; (void)out_size; (void)ws_size;
}

// Round 7
// 2504.439 us; speedup vs baseline: 1.4316x; 1.0459x over previous
//
#include <hip/hip_runtime.h>
#include <math.h>

#define ROI 400
#define HEADS 4
#define DH 100
#define NB 64
#define HIDF 800
#define NC 2
#define KPOOL 280
#define ATT_SCALE 0.1f

typedef __attribute__((ext_vector_type(8))) short short8v;
typedef __attribute__((ext_vector_type(8))) unsigned short u16x8;
typedef __attribute__((ext_vector_type(4))) float f32x4;

union U8 { short8v v; unsigned short u[8]; };

__device__ __forceinline__ unsigned short f2bf(float x) {
  unsigned int u = __float_as_uint(x);
  u += 0x7fffu + ((u >> 16) & 1u);
  return (unsigned short)(u >> 16);
}
__device__ __forceinline__ void split2(float x, unsigned short& h, unsigned short& l) {
  h = f2bf(x);
  float hf = __uint_as_float(((unsigned int)h) << 16);
  l = f2bf(x - hf);
}

// ---------------------------------------------------------------- preprocess
__global__ __launch_bounds__(256) void pre_reduce_kernel(const float* __restrict__ in,
                                                         float* __restrict__ meanb,
                                                         float* __restrict__ stdb) {
  int b = blockIdx.x;
  const float* p = in + (size_t)b * ROI * (2 * ROI);
  double s = 0.0, ss = 0.0;
  const int n = ROI * ROI;
  for (int e = threadIdx.x; e < n; e += blockDim.x) {
    int r = e / ROI, c = e % ROI;
    float v = log10f(p[(size_t)r * (2 * ROI) + ROI + c] + 1.0f);
    s += v; ss += (double)v * (double)v;
  }
  __shared__ double rs[256], rss[256];
  rs[threadIdx.x] = s; rss[threadIdx.x] = ss;
  __syncthreads();
  for (int st = 128; st > 0; st >>= 1) {
    if (threadIdx.x < st) { rs[threadIdx.x] += rs[threadIdx.x + st]; rss[threadIdx.x] += rss[threadIdx.x + st]; }
    __syncthreads();
  }
  if (threadIdx.x == 0) {
    double mean = rs[0] / n;
    double var = (rss[0] - rs[0] * rs[0] / n) / (double)(n - 1);
    meanb[b] = (float)mean;
    stdb[b]  = (float)(sqrt(var) + 1e-6);
  }
}

__global__ __launch_bounds__(256) void build_m_kernel(const float* __restrict__ in,
                                                      const float* __restrict__ sel,
                                                      const float* __restrict__ meanb,
                                                      const float* __restrict__ stdb,
                                                      float* __restrict__ M) {
  size_t e = (size_t)blockIdx.x * blockDim.x + threadIdx.x;
  const size_t total = (size_t)NB * ROI * ROI;
  if (e >= total) return;
  int c = (int)(e % ROI);
  int r = (int)((e / ROI) % ROI);
  int b = (int)(e / ((size_t)ROI * ROI));
  const float* row = in + ((size_t)b * ROI + r) * (2 * ROI);
  float v = log10f(row[ROI + c] + 1.0f);
  float sg = 1.0f / (1.0f + expf(-sel[r * ROI + c]));
  M[e] = ((v - meanb[b]) / stdb[b]) * sg;
}

// ---------------------------------------------------------------- weight pack: W[K][N] -> WT hi/lo [N][K]
__global__ __launch_bounds__(256) void packw_kernel(const float* __restrict__ W, int K, int N,
                                                    unsigned short* __restrict__ WH,
                                                    unsigned short* __restrict__ WL) {
  __shared__ float t[64][68];
  int bk = blockIdx.y * 64, bn = blockIdx.x * 64;
  int r = threadIdx.x >> 2;
  int c0 = (threadIdx.x & 3) << 4;
  int gk = bk + r;
#pragma unroll
  for (int i = 0; i < 4; ++i) {
    int c = c0 + 4 * i;
    float4 v = make_float4(0.f, 0.f, 0.f, 0.f);
    if (gk < K && bn + c < N) v = *(const float4*)(W + (size_t)gk * N + bn + c);
    *(float4*)&t[r][c] = v;
  }
  __syncthreads();
  int gn = bn + r;
#pragma unroll
  for (int i = 0; i < 4; ++i) {
    int c = c0 + 4 * i;
    int gkk = bk + c;
    if (gn < N && gkk < K) {
      ushort4 h, l;
      split2(t[c + 0][r], h.x, l.x);
      split2(t[c + 1][r], h.y, l.y);
      split2(t[c + 2][r], h.z, l.z);
      split2(t[c + 3][r], h.w, l.w);
      *(ushort4*)(WH + (size_t)gn * K + gkk) = h;
      *(ushort4*)(WL + (size_t)gn * K + gkk) = l;
    }
  }
}

// ---------------------------------------------------------------- activation pack: A[M][K](lda) -> hi/lo [M][K]
__global__ __launch_bounds__(256) void packa_kernel(const float* __restrict__ A, int lda, int K, int total4,
                                                    unsigned short* __restrict__ AH,
                                                    unsigned short* __restrict__ AL) {
  int e = blockIdx.x * 256 + threadIdx.x;
  if (e >= total4) return;
  int idx = e << 2;
  int row = idx / K, k = idx - row * K;
  float4 v = *(const float4*)(A + (size_t)row * lda + k);
  ushort4 h, l;
  split2(v.x, h.x, l.x); split2(v.y, h.y, l.y);
  split2(v.z, h.z, l.z); split2(v.w, h.w, l.w);
  *(ushort4*)(AH + (size_t)row * K + k) = h;
  *(ushort4*)(AL + (size_t)row * K + k) = l;
}

// ---------------------------------------------------------------- MFMA split-bf16 GEMM (pre-split A planes)
// EPI: 0 plain, 2 +bias+res(ldr), 4 +bias+gelu -> split u16 out (CH/CL)
#define TBM 128
#define TBN 128
#define TBK 32
#define KP 40

template<int EPI>
__global__ __launch_bounds__(256) void mgemm_kernel(const unsigned short* __restrict__ AHp,
                                                    const unsigned short* __restrict__ ALp,
                                                    const unsigned short* __restrict__ WH,
                                                    const unsigned short* __restrict__ WL,
                                                    const float* __restrict__ bias,
                                                    const float* __restrict__ res, int ldr,
                                                    float* __restrict__ C,
                                                    unsigned short* __restrict__ CH,
                                                    unsigned short* __restrict__ CL,
                                                    int M, int N, int K) {
  __shared__ unsigned short Ah[TBM][KP], Al[TBM][KP], Bh[TBN][KP], Bl[TBN][KP];
  const int tid = threadIdx.x;
  const int lane = tid & 63;
  const int wid = tid >> 6;
  const int wm = wid >> 1, wn = wid & 1;
  const int l15 = lane & 15, l4 = lane >> 4;
  const int bm = blockIdx.y * TBM;
  const int bn = blockIdx.x * TBN;

  f32x4 acc[4][4];
#pragma unroll
  for (int i = 0; i < 4; ++i)
#pragma unroll
    for (int j = 0; j < 4; ++j) acc[i][j] = (f32x4){0.f, 0.f, 0.f, 0.f};

  for (int k0 = 0; k0 < K; k0 += TBK) {
#pragma unroll
    for (int it = 0; it < 2; ++it) {
      int c = tid + 256 * it;
      int row = c >> 2;
      int kq = (c & 3) << 3;
      u16x8 vh = {0, 0, 0, 0, 0, 0, 0, 0};
      u16x8 vl = {0, 0, 0, 0, 0, 0, 0, 0};
      if (k0 + kq + 8 <= K) {
        size_t off = (size_t)(bm + row) * K + k0 + kq;
        vh = *(const u16x8*)(AHp + off);
        vl = *(const u16x8*)(ALp + off);
      }
      *(u16x8*)&Ah[row][kq] = vh;
      *(u16x8*)&Al[row][kq] = vl;
    }
#pragma unroll
    for (int it = 0; it < 2; ++it) {
      int c = tid + 256 * it;
      int row = c >> 2;
      int kq = (c & 3) << 3;
      int gn = bn + row;
      u16x8 vh = {0, 0, 0, 0, 0, 0, 0, 0};
      u16x8 vl = {0, 0, 0, 0, 0, 0, 0, 0};
      if (gn < N && k0 + kq + 8 <= K) {
        size_t off = (size_t)gn * K + k0 + kq;
        vh = *(const u16x8*)(WH + off);
        vl = *(const u16x8*)(WL + off);
      }
      *(u16x8*)&Bh[row][kq] = vh;
      *(u16x8*)&Bl[row][kq] = vl;
    }
    __syncthreads();

    short8v ah[4], alo[4], bh[4], blo[4];
#pragma unroll
    for (int mf = 0; mf < 4; ++mf) {
      int r = wm * 64 + mf * 16 + l15;
      ah[mf]  = *(const short8v*)&Ah[r][l4 * 8];
      alo[mf] = *(const short8v*)&Al[r][l4 * 8];
    }
#pragma unroll
    for (int nf = 0; nf < 4; ++nf) {
      int r = wn * 64 + nf * 16 + l15;
      bh[nf]  = *(const short8v*)&Bh[r][l4 * 8];
      blo[nf] = *(const short8v*)&Bl[r][l4 * 8];
    }
#pragma unroll
    for (int mf = 0; mf < 4; ++mf)
#pragma unroll
      for (int nf = 0; nf < 4; ++nf) {
        acc[mf][nf] = __builtin_amdgcn_mfma_f32_16x16x32_bf16(ah[mf], bh[nf], acc[mf][nf], 0, 0, 0);
        acc[mf][nf] = __builtin_amdgcn_mfma_f32_16x16x32_bf16(ah[mf], blo[nf], acc[mf][nf], 0, 0, 0);
        acc[mf][nf] = __builtin_amdgcn_mfma_f32_16x16x32_bf16(alo[mf], bh[nf], acc[mf][nf], 0, 0, 0);
      }
    __syncthreads();
  }

#pragma unroll
  for (int mf = 0; mf < 4; ++mf) {
#pragma unroll
    for (int nf = 0; nf < 4; ++nf) {
      int col = bn + wn * 64 + nf * 16 + l15;
      if (col < N) {
        float bv = (EPI >= 1) ? bias[col] : 0.f;
        int row0 = bm + wm * 64 + mf * 16 + l4 * 4;
#pragma unroll
        for (int r = 0; r < 4; ++r) {
          float v = acc[mf][nf][r] + bv;
          int row = row0 + r;
          if (EPI == 2) v += res[(size_t)row * ldr + col];
          if (EPI == 4) {
            v = 0.5f * v * (1.0f + erff(v * 0.70710678118654752f));
            unsigned short hh, ll;
            split2(v, hh, ll);
            CH[(size_t)row * N + col] = hh;
            CL[(size_t)row * N + col] = ll;
          } else {
            C[(size_t)row * N + col] = v;
          }
        }
      }
    }
  }
}

// ---------------------------------------------------------------- MFMA flash attention
#define FBJ 32

__global__ __launch_bounds__(256) void fattn_kernel(const float* __restrict__ Q, const float* __restrict__ Kg,
                                                    const float* __restrict__ Vg, const float* __restrict__ Mm,
                                                    float* __restrict__ O, int N, int ldq) {
  __shared__ unsigned short Kh[FBJ][136], Kl[FBJ][136];   // [kv][d pad]
  __shared__ unsigned short Vth[112][40], Vtl[112][40];   // [d pad][kv pad]
  __shared__ unsigned short Ph[64][40], Pl[64][40];       // [q][kv pad]

  const int tid = threadIdx.x;
  const int lane = tid & 63;
  const int w = tid >> 6;
  const int l15 = lane & 15, l4 = lane >> 4;
  const int i0 = blockIdx.x * 64;
  const int h = blockIdx.y, b = blockIdx.z;
  const int HD = HEADS * DH;

  const float* Qb = Q + (size_t)b * N * ldq + h * DH;
  const float* Kb = Kg + (size_t)b * N * ldq + h * DH;
  const float* Vb = Vg + (size_t)b * N * ldq + h * DH;
  const float* Mb = Mm + (size_t)b * N * N;

  // zero V pad rows d=100..111
  for (int e = tid; e < 12 * 40; e += 256) {
    Vth[100 + e / 40][e % 40] = 0; Vtl[100 + e / 40][e % 40] = 0;
  }

  // Q A-fragments (float4 loads): q row = i0+16w+l15, k = kg*32 + l4*8 + j
  int qr = i0 + 16 * w + l15; if (qr >= N) qr = N - 1;
  const float* qrow = Qb + (size_t)qr * ldq;
  short8v qh[4], ql[4];
#pragma unroll
  for (int kg = 0; kg < 4; ++kg) {
    int d0v = kg * 32 + l4 * 8;
    U8 th, tl;
    if (d0v + 7 < DH) {
      float4 x0 = *(const float4*)(qrow + d0v);
      float4 x1 = *(const float4*)(qrow + d0v + 4);
      split2(x0.x, th.u[0], tl.u[0]); split2(x0.y, th.u[1], tl.u[1]);
      split2(x0.z, th.u[2], tl.u[2]); split2(x0.w, th.u[3], tl.u[3]);
      split2(x1.x, th.u[4], tl.u[4]); split2(x1.y, th.u[5], tl.u[5]);
      split2(x1.z, th.u[6], tl.u[6]); split2(x1.w, th.u[7], tl.u[7]);
    } else if (d0v < DH) {
      float4 x0 = *(const float4*)(qrow + d0v);
      split2(x0.x, th.u[0], tl.u[0]); split2(x0.y, th.u[1], tl.u[1]);
      split2(x0.z, th.u[2], tl.u[2]); split2(x0.w, th.u[3], tl.u[3]);
#pragma unroll
      for (int j = 4; j < 8; ++j) { th.u[j] = 0; tl.u[j] = 0; }
    } else {
#pragma unroll
      for (int j = 0; j < 8; ++j) { th.u[j] = 0; tl.u[j] = 0; }
    }
    qh[kg] = th.v; ql[kg] = tl.v;
  }

  float m_i[4], l_i[4];
  f32x4 o[7];
#pragma unroll
  for (int r = 0; r < 4; ++r) { m_i[r] = -INFINITY; l_i[r] = 0.f; }
#pragma unroll
  for (int ff = 0; ff < 7; ++ff) o[ff] = (f32x4){0.f, 0.f, 0.f, 0.f};

  const int njt = (N + FBJ - 1) / FBJ;
  for (int jt = 0; jt < njt; ++jt) {
    const int j0 = jt * FBJ;
    __syncthreads();
    // stage K split: ushort4 rows (2-way banks, free)
    for (int e = tid; e < 32 * 32; e += 256) {
      int kv = e >> 5;
      int dq = (e & 31) << 2;
      int gj = j0 + kv; if (gj >= N) gj = N - 1;
      float4 t = make_float4(0.f, 0.f, 0.f, 0.f);
      if (dq + 3 < DH) t = *(const float4*)(Kb + (size_t)gj * ldq + dq);
      ushort4 hh, ll;
      split2(t.x, hh.x, ll.x); split2(t.y, hh.y, ll.y);
      split2(t.z, hh.z, ll.z); split2(t.w, hh.w, ll.w);
      *(ushort4*)&Kh[kv][dq] = hh;
      *(ushort4*)&Kl[kv][dq] = ll;
    }
    // stage V transposed: lane = (dq group, kv pair) -> packed u32 stores, conflict-free
    for (int e = tid; e < 400; e += 256) {
      int kvp = e & 15;
      int dq = (e >> 4) << 2;
      int gj0 = j0 + 2 * kvp;     if (gj0 >= N) gj0 = N - 1;
      int gj1 = j0 + 2 * kvp + 1; if (gj1 >= N) gj1 = N - 1;
      float4 va = *(const float4*)(Vb + (size_t)gj0 * ldq + dq);
      float4 vbv = *(const float4*)(Vb + (size_t)gj1 * ldq + dq);
      unsigned short ha[4], la[4], hb[4], lb[4];
      split2(va.x, ha[0], la[0]); split2(va.y, ha[1], la[1]);
      split2(va.z, ha[2], la[2]); split2(va.w, ha[3], la[3]);
      split2(vbv.x, hb[0], lb[0]); split2(vbv.y, hb[1], lb[1]);
      split2(vbv.z, hb[2], lb[2]); split2(vbv.w, hb[3], lb[3]);
#pragma unroll
      for (int d = 0; d < 4; ++d) {
        *(unsigned int*)&Vth[dq + d][2 * kvp] = (unsigned int)ha[d] | ((unsigned int)hb[d] << 16);
        *(unsigned int*)&Vtl[dq + d][2 * kvp] = (unsigned int)la[d] | ((unsigned int)lb[d] << 16);
      }
    }
    __syncthreads();

    // QK^T
    f32x4 sacc[2];
    sacc[0] = (f32x4){0.f, 0.f, 0.f, 0.f};
    sacc[1] = (f32x4){0.f, 0.f, 0.f, 0.f};
#pragma unroll
    for (int kg = 0; kg < 4; ++kg) {
#pragma unroll
      for (int f = 0; f < 2; ++f) {
        short8v bh = *(const short8v*)&Kh[l15 + 16 * f][kg * 32 + l4 * 8];
        short8v bl = *(const short8v*)&Kl[l15 + 16 * f][kg * 32 + l4 * 8];
        sacc[f] = __builtin_amdgcn_mfma_f32_16x16x32_bf16(qh[kg], bh, sacc[f], 0, 0, 0);
        sacc[f] = __builtin_amdgcn_mfma_f32_16x16x32_bf16(qh[kg], bl, sacc[f], 0, 0, 0);
        sacc[f] = __builtin_amdgcn_mfma_f32_16x16x32_bf16(ql[kg], bh, sacc[f], 0, 0, 0);
      }
    }

    // softmax + P store
    const int kv0 = j0 + l15, kv1 = j0 + l15 + 16;
#pragma unroll
    for (int r = 0; r < 4; ++r) {
      int gq = i0 + 16 * w + l4 * 4 + r;
      int gqc = (gq < N) ? gq : N - 1;
      const float* Mr = Mb + (size_t)gqc * N;
      float s0 = -INFINITY, s1 = -INFINITY;
      if (kv0 < N) s0 = sacc[0][r] * ATT_SCALE * (1.0f + Mr[kv0]);
      if (kv1 < N) s1 = sacc[1][r] * ATT_SCALE * (1.0f + Mr[kv1]);
      float rm = fmaxf(s0, s1);
      rm = fmaxf(rm, __shfl_xor(rm, 1, 16));
      rm = fmaxf(rm, __shfl_xor(rm, 2, 16));
      rm = fmaxf(rm, __shfl_xor(rm, 4, 16));
      rm = fmaxf(rm, __shfl_xor(rm, 8, 16));
      float nm = fmaxf(m_i[r], rm);
      float fr = expf(m_i[r] - nm);
      float p0 = (kv0 < N) ? expf(s0 - nm) : 0.f;
      float p1 = (kv1 < N) ? expf(s1 - nm) : 0.f;
      float ts = p0 + p1;
      ts += __shfl_xor(ts, 1, 16);
      ts += __shfl_xor(ts, 2, 16);
      ts += __shfl_xor(ts, 4, 16);
      ts += __shfl_xor(ts, 8, 16);
      l_i[r] = l_i[r] * fr + ts;
      m_i[r] = nm;
#pragma unroll
      for (int ff = 0; ff < 7; ++ff) o[ff][r] *= fr;
      unsigned short h0, l0, h1, l1;
      split2(p0, h0, l0); split2(p1, h1, l1);
      int prow = 16 * w + l4 * 4 + r;
      Ph[prow][l15] = h0;      Pl[prow][l15] = l0;
      Ph[prow][l15 + 16] = h1; Pl[prow][l15 + 16] = l1;
    }
    __syncthreads();

    // PV
    short8v ph = *(const short8v*)&Ph[16 * w + l15][l4 * 8];
    short8v pl = *(const short8v*)&Pl[16 * w + l15][l4 * 8];
#pragma unroll
    for (int ff = 0; ff < 7; ++ff) {
      short8v vh = *(const short8v*)&Vth[ff * 16 + l15][l4 * 8];
      short8v vl = *(const short8v*)&Vtl[ff * 16 + l15][l4 * 8];
      o[ff] = __builtin_amdgcn_mfma_f32_16x16x32_bf16(ph, vh, o[ff], 0, 0, 0);
      o[ff] = __builtin_amdgcn_mfma_f32_16x16x32_bf16(ph, vl, o[ff], 0, 0, 0);
      o[ff] = __builtin_amdgcn_mfma_f32_16x16x32_bf16(pl, vh, o[ff], 0, 0, 0);
    }
  }

  float* Ob = O + (size_t)b * N * HD + h * DH;
#pragma unroll
  for (int r = 0; r < 4; ++r) {
    int gq = i0 + 16 * w + l4 * 4 + r;
    if (gq < N) {
      float inv = 1.0f / l_i[r];
#pragma unroll
      for (int ff = 0; ff < 7; ++ff) {
        int d = ff * 16 + l15;
        if (d < DH) Ob[(size_t)gq * HD + d] = o[ff][r] * inv;
      }
    }
  }
}

// ---------------------------------------------------------------- layernorm
__global__ __launch_bounds__(128) void ln_kernel(const float* __restrict__ Y, const float* __restrict__ g,
                                                 const float* __restrict__ bta, float* __restrict__ X) {
  int row = blockIdx.x;
  const float* y = Y + (size_t)row * ROI;
  float* x = X + (size_t)row * ROI;
  int tid = threadIdx.x;
  __shared__ float red[128];
  float s = 0.f;
  for (int c = tid; c < ROI; c += 128) s += y[c];
  red[tid] = s; __syncthreads();
  for (int st = 64; st > 0; st >>= 1) { if (tid < st) red[tid] += red[tid + st]; __syncthreads(); }
  float mu = red[0] / ROI;
  __syncthreads();
  float v = 0.f;
  for (int c = tid; c < ROI; c += 128) { float d = y[c] - mu; v += d * d; }
  red[tid] = v; __syncthreads();
  for (int st = 64; st > 0; st >>= 1) { if (tid < st) red[tid] += red[tid + st]; __syncthreads(); }
  float rstd = rsqrtf(red[0] / ROI + 1e-5f);
  for (int c = tid; c < ROI; c += 128) x[c] = (y[c] - mu) * rstd * g[c] + bta[c];
}

// ---------------------------------------------------------------- classifier head
__global__ __launch_bounds__(128) void cls_kernel(const float* __restrict__ X, const float* __restrict__ r1w,
                                                  const float* __restrict__ r1b, const float* __restrict__ r2w,
                                                  const float* __restrict__ r2b, float* __restrict__ probs, int N) {
  int b = blockIdx.x, tid = threadIdx.x;
  __shared__ float gf[ROI];
  __shared__ float hid[128];
  for (int c = tid; c < ROI; c += 128) {
    float s = 0.f;
    for (int n = 0; n < N; ++n) s += X[((size_t)b * N + n) * ROI + c];
    gf[c] = s / (float)N;
  }
  __syncthreads();
  {
    float a = r1b[tid];
    for (int k = 0; k < ROI; ++k) a += gf[k] * r1w[k * 128 + tid];
    hid[tid] = (a >= 0.f) ? a : 0.01f * a;
  }
  __syncthreads();
  if (tid < NC) {
    float l = r2b[tid];
    for (int k = 0; k < 128; ++k) l += hid[k] * r2w[k * NC + tid];
    gf[tid] = l;
  }
  __syncthreads();
  if (tid == 0) {
    float m = fmaxf(gf[0], gf[1]);
    float e0 = expf(gf[0] - m), e1 = expf(gf[1] - m);
    float inv = 1.f / (e0 + e1);
    probs[b * NC + 0] = e0 * inv;
    probs[b * NC + 1] = e1 * inv;
  }
}

// ---------------------------------------------------------------- pooling
__global__ __launch_bounds__(128) void score_kernel(const float* __restrict__ M, const float* __restrict__ X,
                                                    const float* __restrict__ pws, const float* __restrict__ pwf,
                                                    const float* __restrict__ pmw, const float* __restrict__ pmb,
                                                    float* __restrict__ scores) {
  int i = blockIdx.x, b = blockIdx.y, tid = threadIdx.x;
  const float* mr = M + ((size_t)b * ROI + i) * ROI;
  const float* xr = X + ((size_t)b * ROI + i) * ROI;
  float s1 = 0.f, s2 = 0.f;
  for (int j = tid; j < ROI; j += 128) { s1 += mr[j] * pws[j]; s2 += xr[j] * pwf[j]; }
  __shared__ float r1[128], r2[128];
  r1[tid] = s1; r2[tid] = s2; __syncthreads();
  for (int st = 64; st > 0; st >>= 1) {
    if (tid < st) { r1[tid] += r1[tid + st]; r2[tid] += r2[tid + st]; }
    __syncthreads();
  }
  if (tid == 0) {
    float a = fabsf(r1[0]), c = fabsf(r2[0]);
    float z = a * pmw[0] + c * pmw[1] + pmb[0];
    scores[b * ROI + i] = 1.f / (1.f + expf(-z));
  }
}

__global__ __launch_bounds__(128) void select_kernel(const float* __restrict__ scores, int* __restrict__ idx) {
  int b = blockIdx.x, tid = threadIdx.x;
  __shared__ float sc[ROI];
  __shared__ int sel[ROI];
  for (int i = tid; i < ROI; i += 128) sc[i] = scores[b * ROI + i];
  __syncthreads();
  for (int i = tid; i < ROI; i += 128) {
    float si = sc[i];
    int rank = 0;
    for (int j = 0; j < ROI; ++j) {
      float sj = sc[j];
      rank += (sj > si) || (sj == si && j < i);
    }
    sel[i] = (rank < KPOOL) ? 1 : 0;
  }
  __syncthreads();
  for (int i = tid; i < ROI; i += 128) {
    if (sel[i]) {
      int pos = 0;
      for (int j = 0; j < i; ++j) pos += sel[j];
      idx[b * KPOOL + pos] = i;
    }
  }
}

__global__ __launch_bounds__(128) void gatherx_kernel(const float* __restrict__ X, const float* __restrict__ scores,
                                                      const int* __restrict__ idx, float* __restrict__ Xp) {
  int p = blockIdx.x % KPOOL, b = blockIdx.x / KPOOL, tid = threadIdx.x;
  int src = idx[b * KPOOL + p];
  float sw = scores[b * ROI + src];
  const float* xr = X + ((size_t)b * ROI + src) * ROI;
  float* o = Xp + ((size_t)b * KPOOL + p) * ROI;
  for (int c = tid; c < ROI; c += 128) o[c] = xr[c] * sw;
}

__global__ __launch_bounds__(128) void gatherm_kernel(const float* __restrict__ M, const int* __restrict__ idx,
                                                      float* __restrict__ Mp) {
  int p = blockIdx.x % KPOOL, b = blockIdx.x / KPOOL, tid = threadIdx.x;
  __shared__ int id[KPOOL];
  for (int q = tid; q < KPOOL; q += 128) id[q] = idx[b * KPOOL + q];
  __syncthreads();
  int src = idx[b * KPOOL + p];
  const float* mr = M + ((size_t)b * ROI + src) * ROI;
  float* o = Mp + ((size_t)b * KPOOL + p) * KPOOL;
  for (int q = tid; q < KPOOL; q += 128) o[q] = mr[id[q]];
}

// ---------------------------------------------------------------- final output
__global__ __launch_bounds__(128) void final_kernel(const float* __restrict__ X, const float* __restrict__ probs,
                                                    float* __restrict__ out, int N) {
  int b = blockIdx.x, tid = threadIdx.x;
  __shared__ float f[ROI];
  __shared__ float red[128];
  for (int c = tid; c < ROI; c += 128) {
    float s = 0.f;
    for (int n = 0; n < N; ++n) s += X[((size_t)b * N + n) * ROI + c];
    f[c] = s / (float)N;
  }
  __syncthreads();
  float ls = 0.f;
  for (int c = tid; c < ROI; c += 128) ls += f[c] * f[c];
  red[tid] = ls; __syncthreads();
  for (int st = 64; st > 0; st >>= 1) { if (tid < st) red[tid] += red[tid + st]; __syncthreads(); }
  float inv = 1.f / fmaxf(sqrtf(red[0]), 1e-12f);
  for (int c = tid; c < ROI; c += 128) out[b * ROI + c] = f[c] * inv;
  if (tid < NC) out[NB * ROI + b * NC + tid] = 0.5f * (probs[b * NC + tid] + probs[NB * NC + b * NC + tid]);
}

// ---------------------------------------------------------------- host orchestration
template<int EPI>
static inline void mgemm(const unsigned short* AH, const unsigned short* AL,
                         const unsigned short* WH, const unsigned short* WL,
                         const float* bias, const float* res, int ldr,
                         float* C, unsigned short* CH, unsigned short* CL,
                         int M, int N, int K, hipStream_t st) {
  dim3 g((N + TBN - 1) / TBN, M / TBM);
  mgemm_kernel<EPI><<<g, 256, 0, st>>>(AH, AL, WH, WL, bias, res, ldr, C, CH, CL, M, N, K);
}

static inline void packw(const float* W, int K, int N, unsigned short* WH, unsigned short* WL, hipStream_t st) {
  dim3 g((N + 63) / 64, (K + 63) / 64);
  packw_kernel<<<g, 256, 0, st>>>(W, K, N, WH, WL);
}

static inline void packa(const float* A, int lda, int M, int K, unsigned short* AH, unsigned short* AL,
                         hipStream_t st) {
  int total4 = M * K / 4;
  packa_kernel<<<(total4 + 255) / 256, 256, 0, st>>>(A, lda, K, total4, AH, AL);
}

extern "C" void kernel_launch(void* const* d_in, const int* in_sizes, int n_in,
                              void* d_out, int out_size, void* d_ws, size_t ws_size,
                              hipStream_t stream) {
  const float* in  = (const float*)d_in[0];
  const float* sel = (const float*)d_in[1];
  const float* wq  = (const float*)d_in[2];
  const float* wk  = (const float*)d_in[3];
  const float* wv  = (const float*)d_in[4];
  const float* wo  = (const float*)d_in[5];
  const float* bo  = (const float*)d_in[6];
  const float* w1  = (const float*)d_in[7];
  const float* b1  = (const float*)d_in[8];
  const float* w2  = (const float*)d_in[9];
  const float* b2  = (const float*)d_in[10];
  const float* lng = (const float*)d_in[11];
  const float* lnb = (const float*)d_in[12];
  const float* pws = (const float*)d_in[13];
  const float* pwf = (const float*)d_in[14];
  const float* pmw = (const float*)d_in[15];
  const float* pmb = (const float*)d_in[16];
  const float* r1w = (const float*)d_in[17];
  const float* r1b = (const float*)d_in[18];
  const float* r2w = (const float*)d_in[19];
  const float* r2b = (const float*)d_in[20];
  float* out = (float*)d_out;

  float* ws = (float*)d_ws;
  const size_t AT = (size_t)NB * ROI * ROI;  // 10,240,000 floats per slab

  unsigned short* up = (unsigned short*)ws;
  unsigned short* qkvH = up;                 // [1200][400]
  unsigned short* qkvL = up + 480000;
  unsigned short* woH  = up + 960000;        // [400][400]
  unsigned short* woL  = up + 1120000;
  unsigned short* w1H  = up + 1280000;       // [800][400]
  unsigned short* w1L  = up + 1600000;
  unsigned short* w2H  = up + 1920000;       // [400][800]
  unsigned short* w2L  = up + 2240000;       // ends 2,880,000 u16 = 1.44M floats < AT

  float* smalls = ws + 6 * AT;
  float* meanb = smalls;
  float* stdb  = smalls + 64;
  float* scores = smalls + 128;
  int*   idx = (int*)(smalls + 128 + NB * ROI);
  float* probs = smalls + 128 + NB * ROI + NB * KPOOL;

  float* Mmask = ws + AT;

  pre_reduce_kernel<<<NB, 256, 0, stream>>>(in, meanb, stdb);
  build_m_kernel<<<(int)((AT + 255) / 256), 256, 0, stream>>>(in, sel, meanb, stdb, Mmask);

  // ---------------- depth 0: N=400, Mtok=25600
  {
    const int N = ROI;
    const int Mtok = NB * N;  // 25600
    packw(wq, ROI, ROI, qkvH + 0,      qkvL + 0,      stream);
    packw(wk, ROI, ROI, qkvH + 160000, qkvL + 160000, stream);
    packw(wv, ROI, ROI, qkvH + 320000, qkvL + 320000, stream);
    packw(wo, ROI, ROI, woH, woL, stream);
    packw(w1, ROI, HIDF, w1H, w1L, stream);
    packw(w2, HIDF, ROI, w2H, w2L, stream);

    unsigned short* AinH = (unsigned short*)(ws + 5 * AT);          // [5AT,6AT): 20.48M u16
    unsigned short* AinL = AinH + (size_t)Mtok * ROI;
    packa(in, 2 * ROI, Mtok, ROI, AinH, AinL, stream);

    float* QKV0 = ws + 2 * AT;                                       // [2AT,5AT)
    mgemm<0>(AinH, AinL, qkvH, qkvL, nullptr, nullptr, 0, QKV0, nullptr, nullptr,
             Mtok, 3 * ROI, ROI, stream);

    float* O0 = ws + 5 * AT;                                         // over Ain planes
    fattn_kernel<<<dim3((N + 63) / 64, HEADS, NB), 256, 0, stream>>>(
        QKV0, QKV0 + ROI, QKV0 + 2 * ROI, Mmask, O0, N, 3 * ROI);

    unsigned short* OpH = (unsigned short*)(ws + 2 * AT);            // over QKV (dead)
    unsigned short* OpL = OpH + (size_t)Mtok * ROI;
    packa(O0, ROI, Mtok, ROI, OpH, OpL, stream);

    float* Xa0 = ws + 3 * AT;
    mgemm<2>(OpH, OpL, woH, woL, bo, in, 2 * ROI, Xa0, nullptr, nullptr,
             Mtok, ROI, ROI, stream);

    unsigned short* XaH = (unsigned short*)(ws + 2 * AT);            // over Op planes
    unsigned short* XaL = XaH + (size_t)Mtok * ROI;
    packa(Xa0, ROI, Mtok, ROI, XaH, XaL, stream);

    unsigned short* Hh = (unsigned short*)(ws + 4 * AT);             // [4AT,5AT)
    unsigned short* Hl = (unsigned short*)(ws + 5 * AT);             // [5AT,6AT) (O0 dead)
    mgemm<4>(XaH, XaL, w1H, w1L, b1, nullptr, 0, nullptr, Hh, Hl,
             Mtok, HIDF, ROI, stream);

    float* Y0 = ws + 2 * AT;                                         // over Xa planes
    mgemm<2>(Hh, Hl, w2H, w2L, b2, Xa0, ROI, Y0, nullptr, nullptr,
             Mtok, ROI, HIDF, stream);

    float* Xn = ws + 4 * AT;                                         // over Hh
    ln_kernel<<<Mtok, 128, 0, stream>>>(Y0, lng, lnb, Xn);
    cls_kernel<<<NB, 128, 0, stream>>>(Xn, r1w, r1b, r2w, r2b, probs, N);
    score_kernel<<<dim3(ROI, NB), 128, 0, stream>>>(Mmask, Xn, pws, pwf, pmw, pmb, scores);
    select_kernel<<<NB, 128, 0, stream>>>(scores, idx);
    float* Xp = ws + 5 * AT;                                         // over Hl
    gatherx_kernel<<<NB * KPOOL, 128, 0, stream>>>(Xn, scores, idx, Xp);
    float* Mp = ws + 4 * AT + 5222400;                               // Xn dead by now
    gatherm_kernel<<<NB * KPOOL, 128, 0, stream>>>(Mmask, idx, Mp);
  }

  // ---------------- depth 1: N=280, Mtok=17920
  {
    const int N = KPOOL;
    const int Mtok = NB * N;  // 17920
    const int d = 1;
    const float* wq1 = wq + (size_t)d * ROI * ROI;
    const float* wk1 = wk + (size_t)d * ROI * ROI;
    const float* wv1 = wv + (size_t)d * ROI * ROI;
    const float* wo1 = wo + (size_t)d * ROI * ROI;
    const float* bo1 = bo + (size_t)d * ROI;
    const float* w11 = w1 + (size_t)d * ROI * HIDF;
    const float* b11 = b1 + (size_t)d * HIDF;
    const float* w21 = w2 + (size_t)d * HIDF * ROI;
    const float* b21 = b2 + (size_t)d * ROI;
    const float* lng1 = lng + (size_t)d * ROI;
    const float* lnb1 = lnb + (size_t)d * ROI;
    const float* r1w1 = r1w + (size_t)d * ROI * 128;
    const float* r1b1 = r1b + (size_t)d * 128;
    const float* r2w1 = r2w + (size_t)d * 128 * NC;
    const float* r2b1 = r2b + (size_t)d * NC;

    float* Xp = ws + 5 * AT;
    float* Mp = ws + 4 * AT + 5222400;

    packw(wq1, ROI, ROI, qkvH + 0,      qkvL + 0,      stream);
    packw(wk1, ROI, ROI, qkvH + 160000, qkvL + 160000, stream);
    packw(wv1, ROI, ROI, qkvH + 320000, qkvL + 320000, stream);
    packw(wo1, ROI, ROI, woH, woL, stream);
    packw(w11, ROI, HIDF, w1H, w1L, stream);
    packw(w21, HIDF, ROI, w2H, w2L, stream);

    unsigned short* XpH = (unsigned short*)(ws + AT);                // [1AT, +7.168M F)
    unsigned short* XpL = XpH + (size_t)Mtok * ROI;
    packa(Xp, ROI, Mtok, ROI, XpH, XpL, stream);

    float* QKV1 = ws + 2 * AT;                                       // [2AT, 2AT+21.504M)
    mgemm<0>(XpH, XpL, qkvH, qkvL, nullptr, nullptr, 0, QKV1, nullptr, nullptr,
             Mtok, 3 * ROI, ROI, stream);

    float* O1 = ws + AT;                                             // over Xp planes
    fattn_kernel<<<dim3((N + 63) / 64, HEADS, NB), 256, 0, stream>>>(
        QKV1, QKV1 + ROI, QKV1 + 2 * ROI, Mp, O1, N, 3 * ROI);

    unsigned short* OpH = (unsigned short*)(ws + 2 * AT);            // over QKV1 head
    unsigned short* OpL = OpH + (size_t)Mtok * ROI;
    packa(O1, ROI, Mtok, ROI, OpH, OpL, stream);

    float* Xa1 = ws + 3 * AT;
    mgemm<2>(OpH, OpL, woH, woL, bo1, Xp, ROI, Xa1, nullptr, nullptr,
             Mtok, ROI, ROI, stream);

    unsigned short* XaH = (unsigned short*)(ws + 2 * AT);
    unsigned short* XaL = XaH + (size_t)Mtok * ROI;
    packa(Xa1, ROI, Mtok, ROI, XaH, XaL, stream);

    unsigned short* H1h = (unsigned short*)(ws + 4 * AT);            // [4AT, +14.336M F) — Xp,Mp dead
    unsigned short* H1l = H1h + (size_t)Mtok * HIDF;
    mgemm<4>(XaH, XaL, w1H, w1L, b11, nullptr, 0, nullptr, H1h, H1l,
             Mtok, HIDF, ROI, stream);

    float* Y1 = ws + AT;                                             // over O1
    mgemm<2>(H1h, H1l, w2H, w2L, b21, Xa1, ROI, Y1, nullptr, nullptr,
             Mtok, ROI, HIDF, stream);

    float* Xf = ws + 2 * AT;                                         // over Xa planes
    ln_kernel<<<Mtok, 128, 0, stream>>>(Y1, lng1, lnb1, Xf);
    cls_kernel<<<NB, 128, 0, stream>>>(Xf, r1w1, r1b1, r2w1, r2b1, probs + NB * NC, N);
    final_kernel<<<NB, 128, 0, stream>>>(Xf, probs, out, N);
  }
  (void)in_sizes; (void)n_in; (void)out_size; (void)ws_size;
}

// Round 8
// 1624.222 us; speedup vs baseline: 2.2074x; 1.5419x over previous
//
#include <hip/hip_runtime.h>
#include <math.h>

#define ROI 400
#define HEADS 4
#define DH 100
#define NB 64
#define HIDF 800
#define NC 2
#define KPOOL 280
#define ATT_SCALE 0.1f
#define CTT 10

typedef __attribute__((ext_vector_type(8))) short short8v;
typedef __attribute__((ext_vector_type(8))) unsigned short u16x8;
typedef __attribute__((ext_vector_type(4))) float f32x4;

union U8 { short8v v; unsigned short u[8]; };

__device__ __forceinline__ unsigned short f2bf(float x) {
  unsigned int u = __float_as_uint(x);
  u += 0x7fffu + ((u >> 16) & 1u);
  return (unsigned short)(u >> 16);
}
__device__ __forceinline__ void split2(float x, unsigned short& h, unsigned short& l) {
  h = f2bf(x);
  float hf = __uint_as_float(((unsigned int)h) << 16);
  l = f2bf(x - hf);
}

// ---------------------------------------------------------------- preprocess (two-stage)
__global__ __launch_bounds__(256) void pre_partial_kernel(const float* __restrict__ in,
                                                          double* __restrict__ pp) {
  int b = blockIdx.x, t = blockIdx.y;
  const float* p = in + (size_t)b * ROI * (2 * ROI);
  float s = 0.f, ss = 0.f;
  for (int e = threadIdx.x; e < 40 * ROI; e += 256) {
    int r = 40 * t + e / ROI, c = e % ROI;
    float v = log10f(p[(size_t)r * (2 * ROI) + ROI + c] + 1.0f);
    s += v; ss += v * v;
  }
  __shared__ double rs[256], rss[256];
  rs[threadIdx.x] = s; rss[threadIdx.x] = ss;
  __syncthreads();
  for (int st = 128; st > 0; st >>= 1) {
    if (threadIdx.x < st) { rs[threadIdx.x] += rs[threadIdx.x + st]; rss[threadIdx.x] += rss[threadIdx.x + st]; }
    __syncthreads();
  }
  if (threadIdx.x == 0) {
    pp[(b * CTT + t) * 2 + 0] = rs[0];
    pp[(b * CTT + t) * 2 + 1] = rss[0];
  }
}

__global__ __launch_bounds__(64) void pre_final_kernel(const double* __restrict__ pp,
                                                       float* __restrict__ meanb,
                                                       float* __restrict__ stdb) {
  int b = threadIdx.x;
  double s = 0.0, ss = 0.0;
  for (int t = 0; t < CTT; ++t) { s += pp[(b * CTT + t) * 2]; ss += pp[(b * CTT + t) * 2 + 1]; }
  const int n = ROI * ROI;
  double mean = s / n;
  double var = (ss - s * s / n) / (double)(n - 1);
  meanb[b] = (float)mean;
  stdb[b]  = (float)(sqrt(var) + 1e-6);
}

__global__ __launch_bounds__(256) void build_m_kernel(const float* __restrict__ in,
                                                      const float* __restrict__ sel,
                                                      const float* __restrict__ meanb,
                                                      const float* __restrict__ stdb,
                                                      float* __restrict__ M) {
  size_t e = (size_t)blockIdx.x * blockDim.x + threadIdx.x;
  const size_t total = (size_t)NB * ROI * ROI;
  if (e >= total) return;
  int c = (int)(e % ROI);
  int r = (int)((e / ROI) % ROI);
  int b = (int)(e / ((size_t)ROI * ROI));
  const float* row = in + ((size_t)b * ROI + r) * (2 * ROI);
  float v = log10f(row[ROI + c] + 1.0f);
  float sg = 1.0f / (1.0f + expf(-sel[r * ROI + c]));
  M[e] = ((v - meanb[b]) / stdb[b]) * sg;
}

// ---------------------------------------------------------------- weight pack
__global__ __launch_bounds__(256) void packw_kernel(const float* __restrict__ W, int K, int N,
                                                    unsigned short* __restrict__ WH,
                                                    unsigned short* __restrict__ WL) {
  __shared__ float t[64][68];
  int bk = blockIdx.y * 64, bn = blockIdx.x * 64;
  int r = threadIdx.x >> 2;
  int c0 = (threadIdx.x & 3) << 4;
  int gk = bk + r;
#pragma unroll
  for (int i = 0; i < 4; ++i) {
    int c = c0 + 4 * i;
    float4 v = make_float4(0.f, 0.f, 0.f, 0.f);
    if (gk < K && bn + c < N) v = *(const float4*)(W + (size_t)gk * N + bn + c);
    *(float4*)&t[r][c] = v;
  }
  __syncthreads();
  int gn = bn + r;
#pragma unroll
  for (int i = 0; i < 4; ++i) {
    int c = c0 + 4 * i;
    int gkk = bk + c;
    if (gn < N && gkk < K) {
      ushort4 h, l;
      split2(t[c + 0][r], h.x, l.x);
      split2(t[c + 1][r], h.y, l.y);
      split2(t[c + 2][r], h.z, l.z);
      split2(t[c + 3][r], h.w, l.w);
      *(ushort4*)(WH + (size_t)gn * K + gkk) = h;
      *(ushort4*)(WL + (size_t)gn * K + gkk) = l;
    }
  }
}

// ---------------------------------------------------------------- activation pack
__global__ __launch_bounds__(256) void packa_kernel(const float* __restrict__ A, int lda, int K, int total4,
                                                    unsigned short* __restrict__ AH,
                                                    unsigned short* __restrict__ AL) {
  int e = blockIdx.x * 256 + threadIdx.x;
  if (e >= total4) return;
  int idx = e << 2;
  int row = idx / K, k = idx - row * K;
  float4 v = *(const float4*)(A + (size_t)row * lda + k);
  ushort4 h, l;
  split2(v.x, h.x, l.x); split2(v.y, h.y, l.y);
  split2(v.z, h.z, l.z); split2(v.w, h.w, l.w);
  *(ushort4*)(AH + (size_t)row * K + k) = h;
  *(ushort4*)(AL + (size_t)row * K + k) = l;
}

// ---------------------------------------------------------------- MFMA split-bf16 GEMM
// EPI: 0 plain, 2 bias+res float, 4 bias+gelu -> split out, 5 bias+res -> float + split out
#define TBM 128
#define TBN 128
#define TBK 32
#define KP 40

template<int EPI>
__global__ __launch_bounds__(256) void mgemm_kernel(const unsigned short* __restrict__ AHp,
                                                    const unsigned short* __restrict__ ALp,
                                                    const unsigned short* __restrict__ WH,
                                                    const unsigned short* __restrict__ WL,
                                                    const float* __restrict__ bias,
                                                    const float* __restrict__ res, int ldr,
                                                    float* __restrict__ C,
                                                    unsigned short* __restrict__ CH,
                                                    unsigned short* __restrict__ CL,
                                                    int M, int N, int K) {
  __shared__ unsigned short Ah[TBM][KP], Al[TBM][KP], Bh[TBN][KP], Bl[TBN][KP];
  const int tid = threadIdx.x;
  const int lane = tid & 63;
  const int wid = tid >> 6;
  const int wm = wid >> 1, wn = wid & 1;
  const int l15 = lane & 15, l4 = lane >> 4;
  const int bm = blockIdx.y * TBM;
  const int bn = blockIdx.x * TBN;

  f32x4 acc[4][4];
#pragma unroll
  for (int i = 0; i < 4; ++i)
#pragma unroll
    for (int j = 0; j < 4; ++j) acc[i][j] = (f32x4){0.f, 0.f, 0.f, 0.f};

  for (int k0 = 0; k0 < K; k0 += TBK) {
#pragma unroll
    for (int it = 0; it < 2; ++it) {
      int c = tid + 256 * it;
      int row = c >> 2;
      int kq = (c & 3) << 3;
      u16x8 vh = {0, 0, 0, 0, 0, 0, 0, 0};
      u16x8 vl = {0, 0, 0, 0, 0, 0, 0, 0};
      if (k0 + kq + 8 <= K) {
        size_t off = (size_t)(bm + row) * K + k0 + kq;
        vh = *(const u16x8*)(AHp + off);
        vl = *(const u16x8*)(ALp + off);
      }
      *(u16x8*)&Ah[row][kq] = vh;
      *(u16x8*)&Al[row][kq] = vl;
    }
#pragma unroll
    for (int it = 0; it < 2; ++it) {
      int c = tid + 256 * it;
      int row = c >> 2;
      int kq = (c & 3) << 3;
      int gn = bn + row;
      u16x8 vh = {0, 0, 0, 0, 0, 0, 0, 0};
      u16x8 vl = {0, 0, 0, 0, 0, 0, 0, 0};
      if (gn < N && k0 + kq + 8 <= K) {
        size_t off = (size_t)gn * K + k0 + kq;
        vh = *(const u16x8*)(WH + off);
        vl = *(const u16x8*)(WL + off);
      }
      *(u16x8*)&Bh[row][kq] = vh;
      *(u16x8*)&Bl[row][kq] = vl;
    }
    __syncthreads();

    short8v ah[4], alo[4], bh[4], blo[4];
#pragma unroll
    for (int mf = 0; mf < 4; ++mf) {
      int r = wm * 64 + mf * 16 + l15;
      ah[mf]  = *(const short8v*)&Ah[r][l4 * 8];
      alo[mf] = *(const short8v*)&Al[r][l4 * 8];
    }
#pragma unroll
    for (int nf = 0; nf < 4; ++nf) {
      int r = wn * 64 + nf * 16 + l15;
      bh[nf]  = *(const short8v*)&Bh[r][l4 * 8];
      blo[nf] = *(const short8v*)&Bl[r][l4 * 8];
    }
#pragma unroll
    for (int mf = 0; mf < 4; ++mf)
#pragma unroll
      for (int nf = 0; nf < 4; ++nf) {
        acc[mf][nf] = __builtin_amdgcn_mfma_f32_16x16x32_bf16(ah[mf], bh[nf], acc[mf][nf], 0, 0, 0);
        acc[mf][nf] = __builtin_amdgcn_mfma_f32_16x16x32_bf16(ah[mf], blo[nf], acc[mf][nf], 0, 0, 0);
        acc[mf][nf] = __builtin_amdgcn_mfma_f32_16x16x32_bf16(alo[mf], bh[nf], acc[mf][nf], 0, 0, 0);
      }
    __syncthreads();
  }

#pragma unroll
  for (int mf = 0; mf < 4; ++mf) {
#pragma unroll
    for (int nf = 0; nf < 4; ++nf) {
      int col = bn + wn * 64 + nf * 16 + l15;
      if (col < N) {
        float bv = (EPI >= 1) ? bias[col] : 0.f;
        int row0 = bm + wm * 64 + mf * 16 + l4 * 4;
#pragma unroll
        for (int r = 0; r < 4; ++r) {
          float v = acc[mf][nf][r] + bv;
          int row = row0 + r;
          if (EPI == 2 || EPI == 5) v += res[(size_t)row * ldr + col];
          if (EPI == 4) {
            v = 0.5f * v * (1.0f + erff(v * 0.70710678118654752f));
            unsigned short hh, ll;
            split2(v, hh, ll);
            CH[(size_t)row * N + col] = hh;
            CL[(size_t)row * N + col] = ll;
          } else if (EPI == 5) {
            C[(size_t)row * N + col] = v;
            unsigned short hh, ll;
            split2(v, hh, ll);
            CH[(size_t)row * N + col] = hh;
            CL[(size_t)row * N + col] = ll;
          } else {
            C[(size_t)row * N + col] = v;
          }
        }
      }
    }
  }
}

// ---------------------------------------------------------------- MFMA flash attention (split-plane O out)
#define FBJ 32

__global__ __launch_bounds__(256) void fattn_kernel(const float* __restrict__ Q, const float* __restrict__ Kg,
                                                    const float* __restrict__ Vg, const float* __restrict__ Mm,
                                                    unsigned short* __restrict__ OH,
                                                    unsigned short* __restrict__ OL, int N, int ldq) {
  __shared__ unsigned short Kh[FBJ][136], Kl[FBJ][136];
  __shared__ unsigned short Vth[112][40], Vtl[112][40];
  __shared__ unsigned short Ph[64][40], Pl[64][40];

  const int tid = threadIdx.x;
  const int lane = tid & 63;
  const int w = tid >> 6;
  const int l15 = lane & 15, l4 = lane >> 4;
  const int i0 = blockIdx.x * 64;
  const int h = blockIdx.y, b = blockIdx.z;

  const float* Qb = Q + (size_t)b * N * ldq + h * DH;
  const float* Kb = Kg + (size_t)b * N * ldq + h * DH;
  const float* Vb = Vg + (size_t)b * N * ldq + h * DH;
  const float* Mb = Mm + (size_t)b * N * N;

  for (int e = tid; e < 12 * 40; e += 256) {
    Vth[100 + e / 40][e % 40] = 0; Vtl[100 + e / 40][e % 40] = 0;
  }

  int qr = i0 + 16 * w + l15; if (qr >= N) qr = N - 1;
  const float* qrow = Qb + (size_t)qr * ldq;
  short8v qh[4], ql[4];
#pragma unroll
  for (int kg = 0; kg < 4; ++kg) {
    int d0v = kg * 32 + l4 * 8;
    U8 th, tl;
    if (d0v + 7 < DH) {
      float4 x0 = *(const float4*)(qrow + d0v);
      float4 x1 = *(const float4*)(qrow + d0v + 4);
      split2(x0.x, th.u[0], tl.u[0]); split2(x0.y, th.u[1], tl.u[1]);
      split2(x0.z, th.u[2], tl.u[2]); split2(x0.w, th.u[3], tl.u[3]);
      split2(x1.x, th.u[4], tl.u[4]); split2(x1.y, th.u[5], tl.u[5]);
      split2(x1.z, th.u[6], tl.u[6]); split2(x1.w, th.u[7], tl.u[7]);
    } else if (d0v < DH) {
      float4 x0 = *(const float4*)(qrow + d0v);
      split2(x0.x, th.u[0], tl.u[0]); split2(x0.y, th.u[1], tl.u[1]);
      split2(x0.z, th.u[2], tl.u[2]); split2(x0.w, th.u[3], tl.u[3]);
#pragma unroll
      for (int j = 4; j < 8; ++j) { th.u[j] = 0; tl.u[j] = 0; }
    } else {
#pragma unroll
      for (int j = 0; j < 8; ++j) { th.u[j] = 0; tl.u[j] = 0; }
    }
    qh[kg] = th.v; ql[kg] = tl.v;
  }

  float m_i[4], l_i[4];
  f32x4 o[7];
#pragma unroll
  for (int r = 0; r < 4; ++r) { m_i[r] = -INFINITY; l_i[r] = 0.f; }
#pragma unroll
  for (int ff = 0; ff < 7; ++ff) o[ff] = (f32x4){0.f, 0.f, 0.f, 0.f};

  const int njt = (N + FBJ - 1) / FBJ;
  for (int jt = 0; jt < njt; ++jt) {
    const int j0 = jt * FBJ;
    __syncthreads();
    for (int e = tid; e < 32 * 32; e += 256) {
      int kv = e >> 5;
      int dq = (e & 31) << 2;
      int gj = j0 + kv; if (gj >= N) gj = N - 1;
      float4 t = make_float4(0.f, 0.f, 0.f, 0.f);
      if (dq + 3 < DH) t = *(const float4*)(Kb + (size_t)gj * ldq + dq);
      ushort4 hh, ll;
      split2(t.x, hh.x, ll.x); split2(t.y, hh.y, ll.y);
      split2(t.z, hh.z, ll.z); split2(t.w, hh.w, ll.w);
      *(ushort4*)&Kh[kv][dq] = hh;
      *(ushort4*)&Kl[kv][dq] = ll;
    }
    for (int e = tid; e < 400; e += 256) {
      int kvp = e & 15;
      int dq = (e >> 4) << 2;
      int gj0 = j0 + 2 * kvp;     if (gj0 >= N) gj0 = N - 1;
      int gj1 = j0 + 2 * kvp + 1; if (gj1 >= N) gj1 = N - 1;
      float4 va = *(const float4*)(Vb + (size_t)gj0 * ldq + dq);
      float4 vbv = *(const float4*)(Vb + (size_t)gj1 * ldq + dq);
      unsigned short ha[4], la[4], hb[4], lb[4];
      split2(va.x, ha[0], la[0]); split2(va.y, ha[1], la[1]);
      split2(va.z, ha[2], la[2]); split2(va.w, ha[3], la[3]);
      split2(vbv.x, hb[0], lb[0]); split2(vbv.y, hb[1], lb[1]);
      split2(vbv.z, hb[2], lb[2]); split2(vbv.w, hb[3], lb[3]);
#pragma unroll
      for (int d = 0; d < 4; ++d) {
        *(unsigned int*)&Vth[dq + d][2 * kvp] = (unsigned int)ha[d] | ((unsigned int)hb[d] << 16);
        *(unsigned int*)&Vtl[dq + d][2 * kvp] = (unsigned int)la[d] | ((unsigned int)lb[d] << 16);
      }
    }
    __syncthreads();

    f32x4 sacc[2];
    sacc[0] = (f32x4){0.f, 0.f, 0.f, 0.f};
    sacc[1] = (f32x4){0.f, 0.f, 0.f, 0.f};
#pragma unroll
    for (int kg = 0; kg < 4; ++kg) {
#pragma unroll
      for (int f = 0; f < 2; ++f) {
        short8v bh = *(const short8v*)&Kh[l15 + 16 * f][kg * 32 + l4 * 8];
        short8v bl = *(const short8v*)&Kl[l15 + 16 * f][kg * 32 + l4 * 8];
        sacc[f] = __builtin_amdgcn_mfma_f32_16x16x32_bf16(qh[kg], bh, sacc[f], 0, 0, 0);
        sacc[f] = __builtin_amdgcn_mfma_f32_16x16x32_bf16(qh[kg], bl, sacc[f], 0, 0, 0);
        sacc[f] = __builtin_amdgcn_mfma_f32_16x16x32_bf16(ql[kg], bh, sacc[f], 0, 0, 0);
      }
    }

    const int kv0 = j0 + l15, kv1 = j0 + l15 + 16;
#pragma unroll
    for (int r = 0; r < 4; ++r) {
      int gq = i0 + 16 * w + l4 * 4 + r;
      int gqc = (gq < N) ? gq : N - 1;
      const float* Mr = Mb + (size_t)gqc * N;
      float s0 = -INFINITY, s1 = -INFINITY;
      if (kv0 < N) s0 = sacc[0][r] * ATT_SCALE * (1.0f + Mr[kv0]);
      if (kv1 < N) s1 = sacc[1][r] * ATT_SCALE * (1.0f + Mr[kv1]);
      float rm = fmaxf(s0, s1);
      rm = fmaxf(rm, __shfl_xor(rm, 1, 16));
      rm = fmaxf(rm, __shfl_xor(rm, 2, 16));
      rm = fmaxf(rm, __shfl_xor(rm, 4, 16));
      rm = fmaxf(rm, __shfl_xor(rm, 8, 16));
      float nm = fmaxf(m_i[r], rm);
      float fr = expf(m_i[r] - nm);
      float p0 = (kv0 < N) ? expf(s0 - nm) : 0.f;
      float p1 = (kv1 < N) ? expf(s1 - nm) : 0.f;
      float ts = p0 + p1;
      ts += __shfl_xor(ts, 1, 16);
      ts += __shfl_xor(ts, 2, 16);
      ts += __shfl_xor(ts, 4, 16);
      ts += __shfl_xor(ts, 8, 16);
      l_i[r] = l_i[r] * fr + ts;
      m_i[r] = nm;
#pragma unroll
      for (int ff = 0; ff < 7; ++ff) o[ff][r] *= fr;
      unsigned short h0, l0, h1, l1;
      split2(p0, h0, l0); split2(p1, h1, l1);
      int prow = 16 * w + l4 * 4 + r;
      Ph[prow][l15] = h0;      Pl[prow][l15] = l0;
      Ph[prow][l15 + 16] = h1; Pl[prow][l15 + 16] = l1;
    }
    __syncthreads();

    short8v ph = *(const short8v*)&Ph[16 * w + l15][l4 * 8];
    short8v pl = *(const short8v*)&Pl[16 * w + l15][l4 * 8];
#pragma unroll
    for (int ff = 0; ff < 7; ++ff) {
      short8v vh = *(const short8v*)&Vth[ff * 16 + l15][l4 * 8];
      short8v vl = *(const short8v*)&Vtl[ff * 16 + l15][l4 * 8];
      o[ff] = __builtin_amdgcn_mfma_f32_16x16x32_bf16(ph, vh, o[ff], 0, 0, 0);
      o[ff] = __builtin_amdgcn_mfma_f32_16x16x32_bf16(ph, vl, o[ff], 0, 0, 0);
      o[ff] = __builtin_amdgcn_mfma_f32_16x16x32_bf16(pl, vh, o[ff], 0, 0, 0);
    }
  }

  // epilogue: write O split planes [row=b*N+gq][ROI], col = h*DH + d
#pragma unroll
  for (int r = 0; r < 4; ++r) {
    int gq = i0 + 16 * w + l4 * 4 + r;
    if (gq < N) {
      float inv = 1.0f / l_i[r];
      size_t rowoff = ((size_t)b * N + gq) * ROI + h * DH;
#pragma unroll
      for (int ff = 0; ff < 7; ++ff) {
        int d = ff * 16 + l15;
        if (d < DH) {
          unsigned short hh, ll;
          split2(o[ff][r] * inv, hh, ll);
          OH[rowoff + d] = hh;
          OL[rowoff + d] = ll;
        }
      }
    }
  }
}

// ---------------------------------------------------------------- layernorm
__global__ __launch_bounds__(128) void ln_kernel(const float* __restrict__ Y, const float* __restrict__ g,
                                                 const float* __restrict__ bta, float* __restrict__ X) {
  int row = blockIdx.x;
  const float* y = Y + (size_t)row * ROI;
  float* x = X + (size_t)row * ROI;
  int tid = threadIdx.x;
  __shared__ float red[128];
  float s = 0.f;
  for (int c = tid; c < ROI; c += 128) s += y[c];
  red[tid] = s; __syncthreads();
  for (int st = 64; st > 0; st >>= 1) { if (tid < st) red[tid] += red[tid + st]; __syncthreads(); }
  float mu = red[0] / ROI;
  __syncthreads();
  float v = 0.f;
  for (int c = tid; c < ROI; c += 128) { float d = y[c] - mu; v += d * d; }
  red[tid] = v; __syncthreads();
  for (int st = 64; st > 0; st >>= 1) { if (tid < st) red[tid] += red[tid + st]; __syncthreads(); }
  float rstd = rsqrtf(red[0] / ROI + 1e-5f);
  for (int c = tid; c < ROI; c += 128) x[c] = (y[c] - mu) * rstd * g[c] + bta[c];
}

// ---------------------------------------------------------------- column-mean partials (grid NB x CTT)
__global__ __launch_bounds__(128) void colmean_kernel(const float* __restrict__ X,
                                                      float* __restrict__ gfp, int N) {
  int b = blockIdx.x, t = blockIdx.y, tid = threadIdx.x;
  int per = (N + CTT - 1) / CTT;
  int n0 = t * per, n1 = n0 + per;
  if (n1 > N) n1 = N;
  float a0 = 0.f, a1 = 0.f, a2 = 0.f, a3 = 0.f;
  for (int n = n0; n < n1; ++n) {
    const float* row = X + ((size_t)b * N + n) * ROI;
    a0 += row[tid]; a1 += row[tid + 128]; a2 += row[tid + 256];
    if (tid < 16) a3 += row[tid + 384];
  }
  float* g = gfp + ((size_t)b * CTT + t) * ROI;
  g[tid] = a0; g[tid + 128] = a1; g[tid + 256] = a2;
  if (tid < 16) g[tid + 384] = a3;
}

// ---------------------------------------------------------------- classifier head (from partials)
__global__ __launch_bounds__(128) void head_kernel(const float* __restrict__ gfp,
                                                   const float* __restrict__ r1w, const float* __restrict__ r1b,
                                                   const float* __restrict__ r2w, const float* __restrict__ r2b,
                                                   float* __restrict__ probs, int N) {
  int b = blockIdx.x, tid = threadIdx.x;
  __shared__ float gf[ROI];
  __shared__ float hid[128];
  for (int c = tid; c < ROI; c += 128) {
    float s = 0.f;
    for (int t = 0; t < CTT; ++t) s += gfp[((size_t)b * CTT + t) * ROI + c];
    gf[c] = s / (float)N;
  }
  __syncthreads();
  {
    float a = r1b[tid];
    for (int k = 0; k < ROI; ++k) a += gf[k] * r1w[k * 128 + tid];
    hid[tid] = (a >= 0.f) ? a : 0.01f * a;
  }
  __syncthreads();
  if (tid < NC) {
    float l = r2b[tid];
    for (int k = 0; k < 128; ++k) l += hid[k] * r2w[k * NC + tid];
    gf[tid] = l;
  }
  __syncthreads();
  if (tid == 0) {
    float m = fmaxf(gf[0], gf[1]);
    float e0 = expf(gf[0] - m), e1 = expf(gf[1] - m);
    float inv = 1.f / (e0 + e1);
    probs[b * NC + 0] = e0 * inv;
    probs[b * NC + 1] = e1 * inv;
  }
}

// ---------------------------------------------------------------- final output (from partials)
__global__ __launch_bounds__(128) void finalize_kernel(const float* __restrict__ gfp,
                                                       const float* __restrict__ probs,
                                                       float* __restrict__ out, int N) {
  int b = blockIdx.x, tid = threadIdx.x;
  __shared__ float f[ROI];
  __shared__ float red[128];
  for (int c = tid; c < ROI; c += 128) {
    float s = 0.f;
    for (int t = 0; t < CTT; ++t) s += gfp[((size_t)b * CTT + t) * ROI + c];
    f[c] = s / (float)N;
  }
  __syncthreads();
  float ls = 0.f;
  for (int c = tid; c < ROI; c += 128) ls += f[c] * f[c];
  red[tid] = ls; __syncthreads();
  for (int st = 64; st > 0; st >>= 1) { if (tid < st) red[tid] += red[tid + st]; __syncthreads(); }
  float inv = 1.f / fmaxf(sqrtf(red[0]), 1e-12f);
  for (int c = tid; c < ROI; c += 128) out[b * ROI + c] = f[c] * inv;
  if (tid < NC) out[NB * ROI + b * NC + tid] = 0.5f * (probs[b * NC + tid] + probs[NB * NC + b * NC + tid]);
}

// ---------------------------------------------------------------- pooling
__global__ __launch_bounds__(128) void score_kernel(const float* __restrict__ M, const float* __restrict__ X,
                                                    const float* __restrict__ pws, const float* __restrict__ pwf,
                                                    const float* __restrict__ pmw, const float* __restrict__ pmb,
                                                    float* __restrict__ scores) {
  int i = blockIdx.x, b = blockIdx.y, tid = threadIdx.x;
  const float* mr = M + ((size_t)b * ROI + i) * ROI;
  const float* xr = X + ((size_t)b * ROI + i) * ROI;
  float s1 = 0.f, s2 = 0.f;
  for (int j = tid; j < ROI; j += 128) { s1 += mr[j] * pws[j]; s2 += xr[j] * pwf[j]; }
  __shared__ float r1[128], r2[128];
  r1[tid] = s1; r2[tid] = s2; __syncthreads();
  for (int st = 64; st > 0; st >>= 1) {
    if (tid < st) { r1[tid] += r1[tid + st]; r2[tid] += r2[tid + st]; }
    __syncthreads();
  }
  if (tid == 0) {
    float a = fabsf(r1[0]), c = fabsf(r2[0]);
    float z = a * pmw[0] + c * pmw[1] + pmb[0];
    scores[b * ROI + i] = 1.f / (1.f + expf(-z));
  }
}

__global__ __launch_bounds__(128) void select_kernel(const float* __restrict__ scores, int* __restrict__ idx) {
  int b = blockIdx.x, tid = threadIdx.x;
  __shared__ float sc[ROI];
  __shared__ int sel[ROI];
  for (int i = tid; i < ROI; i += 128) sc[i] = scores[b * ROI + i];
  __syncthreads();
  for (int i = tid; i < ROI; i += 128) {
    float si = sc[i];
    int rank = 0;
    for (int j = 0; j < ROI; ++j) {
      float sj = sc[j];
      rank += (sj > si) || (sj == si && j < i);
    }
    sel[i] = (rank < KPOOL) ? 1 : 0;
  }
  __syncthreads();
  for (int i = tid; i < ROI; i += 128) {
    if (sel[i]) {
      int pos = 0;
      for (int j = 0; j < i; ++j) pos += sel[j];
      idx[b * KPOOL + pos] = i;
    }
  }
}

__global__ __launch_bounds__(128) void gatherx_kernel(const float* __restrict__ X, const float* __restrict__ scores,
                                                      const int* __restrict__ idx, float* __restrict__ Xp) {
  int p = blockIdx.x % KPOOL, b = blockIdx.x / KPOOL, tid = threadIdx.x;
  int src = idx[b * KPOOL + p];
  float sw = scores[b * ROI + src];
  const float* xr = X + ((size_t)b * ROI + src) * ROI;
  float* o = Xp + ((size_t)b * KPOOL + p) * ROI;
  for (int c = tid; c < ROI; c += 128) o[c] = xr[c] * sw;
}

__global__ __launch_bounds__(128) void gatherm_kernel(const float* __restrict__ M, const int* __restrict__ idx,
                                                      float* __restrict__ Mp) {
  int p = blockIdx.x % KPOOL, b = blockIdx.x / KPOOL, tid = threadIdx.x;
  __shared__ int id[KPOOL];
  for (int q = tid; q < KPOOL; q += 128) id[q] = idx[b * KPOOL + q];
  __syncthreads();
  int src = idx[b * KPOOL + p];
  const float* mr = M + ((size_t)b * ROI + src) * ROI;
  float* o = Mp + ((size_t)b * KPOOL + p) * KPOOL;
  for (int q = tid; q < KPOOL; q += 128) o[q] = mr[id[q]];
}

// ---------------------------------------------------------------- host orchestration
template<int EPI>
static inline void mgemm(const unsigned short* AH, const unsigned short* AL,
                         const unsigned short* WH, const unsigned short* WL,
                         const float* bias, const float* res, int ldr,
                         float* C, unsigned short* CH, unsigned short* CL,
                         int M, int N, int K, hipStream_t st) {
  dim3 g((N + TBN - 1) / TBN, M / TBM);
  mgemm_kernel<EPI><<<g, 256, 0, st>>>(AH, AL, WH, WL, bias, res, ldr, C, CH, CL, M, N, K);
}

static inline void packw(const float* W, int K, int N, unsigned short* WH, unsigned short* WL, hipStream_t st) {
  dim3 g((N + 63) / 64, (K + 63) / 64);
  packw_kernel<<<g, 256, 0, st>>>(W, K, N, WH, WL);
}

static inline void packa(const float* A, int lda, int M, int K, unsigned short* AH, unsigned short* AL,
                         hipStream_t st) {
  int total4 = M * K / 4;
  packa_kernel<<<(total4 + 255) / 256, 256, 0, st>>>(A, lda, K, total4, AH, AL);
}

extern "C" void kernel_launch(void* const* d_in, const int* in_sizes, int n_in,
                              void* d_out, int out_size, void* d_ws, size_t ws_size,
                              hipStream_t stream) {
  const float* in  = (const float*)d_in[0];
  const float* sel = (const float*)d_in[1];
  const float* wq  = (const float*)d_in[2];
  const float* wk  = (const float*)d_in[3];
  const float* wv  = (const float*)d_in[4];
  const float* wo  = (const float*)d_in[5];
  const float* bo  = (const float*)d_in[6];
  const float* w1  = (const float*)d_in[7];
  const float* b1  = (const float*)d_in[8];
  const float* w2  = (const float*)d_in[9];
  const float* b2  = (const float*)d_in[10];
  const float* lng = (const float*)d_in[11];
  const float* lnb = (const float*)d_in[12];
  const float* pws = (const float*)d_in[13];
  const float* pwf = (const float*)d_in[14];
  const float* pmw = (const float*)d_in[15];
  const float* pmb = (const float*)d_in[16];
  const float* r1w = (const float*)d_in[17];
  const float* r1b = (const float*)d_in[18];
  const float* r2w = (const float*)d_in[19];
  const float* r2b = (const float*)d_in[20];
  float* out = (float*)d_out;

  float* ws = (float*)d_ws;
  const size_t AT = (size_t)NB * ROI * ROI;  // 10,240,000 floats per slab

  unsigned short* up = (unsigned short*)ws;
  unsigned short* qkvH = up;                 // [1200][400]
  unsigned short* qkvL = up + 480000;
  unsigned short* woH  = up + 960000;        // [400][400]
  unsigned short* woL  = up + 1120000;
  unsigned short* w1H  = up + 1280000;       // [800][400]
  unsigned short* w1L  = up + 1600000;
  unsigned short* w2H  = up + 1920000;       // [400][800]
  unsigned short* w2L  = up + 2240000;       // ends 2.88M u16 = 1.44M floats < AT

  float* smalls = ws + 6 * AT;
  float* meanb = smalls;
  float* stdb  = smalls + 64;
  float* scores = smalls + 128;
  int*   idx = (int*)(smalls + 128 + NB * ROI);
  float* probs = smalls + 128 + NB * ROI + NB * KPOOL;
  double* pp = (double*)(smalls + 128 + NB * ROI + NB * KPOOL + 2 * NB * NC + 16);  // 1280 doubles

  float* Mmask = ws + AT;

  pre_partial_kernel<<<dim3(NB, CTT), 256, 0, stream>>>(in, pp);
  pre_final_kernel<<<1, 64, 0, stream>>>(pp, meanb, stdb);
  build_m_kernel<<<(int)((AT + 255) / 256), 256, 0, stream>>>(in, sel, meanb, stdb, Mmask);

  // ---------------- depth 0: N=400, Mtok=25600
  {
    const int N = ROI;
    const int Mtok = NB * N;  // 25600
    packw(wq, ROI, ROI, qkvH + 0,      qkvL + 0,      stream);
    packw(wk, ROI, ROI, qkvH + 160000, qkvL + 160000, stream);
    packw(wv, ROI, ROI, qkvH + 320000, qkvL + 320000, stream);
    packw(wo, ROI, ROI, woH, woL, stream);
    packw(w1, ROI, HIDF, w1H, w1L, stream);
    packw(w2, HIDF, ROI, w2H, w2L, stream);

    unsigned short* AinH = (unsigned short*)(ws + 5 * AT);
    unsigned short* AinL = AinH + (size_t)Mtok * ROI;
    packa(in, 2 * ROI, Mtok, ROI, AinH, AinL, stream);

    float* QKV0 = ws + 2 * AT;                                       // [2AT,5AT)
    mgemm<0>(AinH, AinL, qkvH, qkvL, nullptr, nullptr, 0, QKV0, nullptr, nullptr,
             Mtok, 3 * ROI, ROI, stream);

    unsigned short* OpH = (unsigned short*)(ws + 5 * AT);            // over Ain planes
    unsigned short* OpL = OpH + (size_t)Mtok * ROI;
    fattn_kernel<<<dim3((N + 63) / 64, HEADS, NB), 256, 0, stream>>>(
        QKV0, QKV0 + ROI, QKV0 + 2 * ROI, Mmask, OpH, OpL, N, 3 * ROI);

    float* Xa0 = ws + 2 * AT;                                        // over QKV0 (dead)
    unsigned short* XaH = (unsigned short*)(ws + 3 * AT);
    unsigned short* XaL = XaH + (size_t)Mtok * ROI;
    mgemm<5>(OpH, OpL, woH, woL, bo, in, 2 * ROI, Xa0, XaH, XaL,
             Mtok, ROI, ROI, stream);

    unsigned short* Hh = (unsigned short*)(ws + 4 * AT);             // [4AT,5AT)
    unsigned short* Hl = (unsigned short*)(ws + 5 * AT);             // [5AT,6AT) — Op dead
    mgemm<4>(XaH, XaL, w1H, w1L, b1, nullptr, 0, nullptr, Hh, Hl,
             Mtok, HIDF, ROI, stream);

    float* Y0 = ws + 3 * AT;                                         // over Xa planes (dead)
    mgemm<2>(Hh, Hl, w2H, w2L, b2, Xa0, ROI, Y0, nullptr, nullptr,
             Mtok, ROI, HIDF, stream);

    float* Xn = ws + 2 * AT;                                         // over Xa0 (dead)
    ln_kernel<<<Mtok, 128, 0, stream>>>(Y0, lng, lnb, Xn);

    float* gfp0 = ws + 3 * AT;                                       // over Y0 (dead)
    colmean_kernel<<<dim3(NB, CTT), 128, 0, stream>>>(Xn, gfp0, N);
    head_kernel<<<NB, 128, 0, stream>>>(gfp0, r1w, r1b, r2w, r2b, probs, N);

    score_kernel<<<dim3(ROI, NB), 128, 0, stream>>>(Mmask, Xn, pws, pwf, pmw, pmb, scores);
    select_kernel<<<NB, 128, 0, stream>>>(scores, idx);
    float* Xp = ws + 5 * AT;                                         // over Hl (dead)
    gatherx_kernel<<<NB * KPOOL, 128, 0, stream>>>(Xn, scores, idx, Xp);
    float* Mp = ws + 4 * AT + 1200000;                               // clear of QKV1's future span
    gatherm_kernel<<<NB * KPOOL, 128, 0, stream>>>(Mmask, idx, Mp);
  }

  // ---------------- depth 1: N=280, Mtok=17920
  {
    const int N = KPOOL;
    const int Mtok = NB * N;  // 17920
    const int d = 1;
    const float* wq1 = wq + (size_t)d * ROI * ROI;
    const float* wk1 = wk + (size_t)d * ROI * ROI;
    const float* wv1 = wv + (size_t)d * ROI * ROI;
    const float* wo1 = wo + (size_t)d * ROI * ROI;
    const float* bo1 = bo + (size_t)d * ROI;
    const float* w11 = w1 + (size_t)d * ROI * HIDF;
    const float* b11 = b1 + (size_t)d * HIDF;
    const float* w21 = w2 + (size_t)d * HIDF * ROI;
    const float* b21 = b2 + (size_t)d * ROI;
    const float* lng1 = lng + (size_t)d * ROI;
    const float* lnb1 = lnb + (size_t)d * ROI;
    const float* r1w1 = r1w + (size_t)d * ROI * 128;
    const float* r1b1 = r1b + (size_t)d * 128;
    const float* r2w1 = r2w + (size_t)d * 128 * NC;
    const float* r2b1 = r2b + (size_t)d * NC;

    float* Xp = ws + 5 * AT;
    float* Mp = ws + 4 * AT + 1200000;

    packw(wq1, ROI, ROI, qkvH + 0,      qkvL + 0,      stream);
    packw(wk1, ROI, ROI, qkvH + 160000, qkvL + 160000, stream);
    packw(wv1, ROI, ROI, qkvH + 320000, qkvL + 320000, stream);
    packw(wo1, ROI, ROI, woH, woL, stream);
    packw(w11, ROI, HIDF, w1H, w1L, stream);
    packw(w21, HIDF, ROI, w2H, w2L, stream);

    unsigned short* XpH = (unsigned short*)(ws + AT);                // over Mmask (dead)
    unsigned short* XpL = XpH + (size_t)Mtok * ROI;
    packa(Xp, ROI, Mtok, ROI, XpH, XpL, stream);

    float* QKV1 = ws + 2 * AT;                                       // [2AT, 2AT+21.504M) < Mp
    mgemm<0>(XpH, XpL, qkvH, qkvL, nullptr, nullptr, 0, QKV1, nullptr, nullptr,
             Mtok, 3 * ROI, ROI, stream);

    unsigned short* OpH = (unsigned short*)(ws + AT);                // over Xp planes (dead)
    unsigned short* OpL = OpH + (size_t)Mtok * ROI;
    fattn_kernel<<<dim3((N + 63) / 64, HEADS, NB), 256, 0, stream>>>(
        QKV1, QKV1 + ROI, QKV1 + 2 * ROI, Mp, OpH, OpL, N, 3 * ROI);

    float* Xa1 = ws + 2 * AT;                                        // over QKV1 (dead)
    unsigned short* XaH = (unsigned short*)(ws + 3 * AT);
    unsigned short* XaL = XaH + (size_t)Mtok * ROI;
    mgemm<5>(OpH, OpL, woH, woL, bo1, Xp, ROI, Xa1, XaH, XaL,
             Mtok, ROI, ROI, stream);

    unsigned short* H1h = (unsigned short*)(ws + 4 * AT);            // Mp dead after fattn
    unsigned short* H1l = (unsigned short*)(ws + 5 * AT);            // Xp dead after Xa1
    mgemm<4>(XaH, XaL, w1H, w1L, b11, nullptr, 0, nullptr, H1h, H1l,
             Mtok, HIDF, ROI, stream);

    float* Y1 = ws + AT;                                             // over Op planes (dead)
    mgemm<2>(H1h, H1l, w2H, w2L, b21, Xa1, ROI, Y1, nullptr, nullptr,
             Mtok, ROI, HIDF, stream);

    float* Xf = ws + 3 * AT;                                         // over Xa planes (dead)
    ln_kernel<<<Mtok, 128, 0, stream>>>(Y1, lng1, lnb1, Xf);

    float* gfp1 = ws + 2 * AT;                                       // over Xa1 (dead)
    colmean_kernel<<<dim3(NB, CTT), 128, 0, stream>>>(Xf, gfp1, N);
    head_kernel<<<NB, 128, 0, stream>>>(gfp1, r1w1, r1b1, r2w1, r2b1, probs + NB * NC, N);
    finalize_kernel<<<NB, 128, 0, stream>>>(gfp1, probs, out, N);
  }
  (void)in_sizes; (void)n_in; (void)out_size; (void)ws_size;
}